// Round 1
// baseline (32781.424 us; speedup 1.0000x reference)
//
#include <hip/hip_runtime.h>
#include <math.h>

#define T_ 32
#define B_ 16
#define TB 512
#define HID 256
#define NA 18
#define HH 27
#define WW 20
#define P_ 540   // 27*20

__device__ __forceinline__ float sigm(float x){ return 1.0f/(1.0f+expf(-x)); }

// ---------------- conv1: (512,3,210,160) -> (512,32,52,40), k8 s4 pad H(1,1) W(2,2)
__global__ __launch_bounds__(256) void conv1k(const float* __restrict__ frame,
                                              const float* __restrict__ w,
                                              const float* __restrict__ bias,
                                              float* __restrict__ out){
    int idx = blockIdx.x*256 + threadIdx.x;
    // 512*32*52*40 = 34,078,720
    int ow = idx % 40;
    int oh = (idx/40) % 52;
    int oc = (idx/2080) % 32;
    int n  = idx / 66560;
    float acc = bias[oc];
    const float* fb = frame + (size_t)n*3*210*160;
    const float* wb = w + oc*192;
    for (int ic=0; ic<3; ++ic){
        const float* fch = fb + ic*210*160;
        const float* wch = wb + ic*64;
        #pragma unroll
        for (int kh=0; kh<8; ++kh){
            int iy = oh*4 - 1 + kh;
            if (iy < 0 || iy >= 210) continue;
            const float* frow = fch + iy*160;
            const float* wrow = wch + kh*8;
            #pragma unroll
            for (int kw=0; kw<8; ++kw){
                int ix = ow*4 - 2 + kw;
                if (ix >= 0 && ix < 160) acc += frow[ix]*wrow[kw];
            }
        }
    }
    out[idx] = acc;
}

// ---------------- conv2: (512,32,52,40) -> (512,64,27,20), k4 s2 pad H(2,2) W(1,1)
__global__ __launch_bounds__(256) void conv2k(const float* __restrict__ c1,
                                              const float* __restrict__ w,
                                              const float* __restrict__ bias,
                                              float* __restrict__ out){
    int idx = blockIdx.x*256 + threadIdx.x;
    // 512*64*540 = 17,694,720
    int ow = idx % 20;
    int oh = (idx/20) % 27;
    int oc = (idx/540) % 64;
    int n  = idx / 34560;
    float acc = bias[oc];
    const float* ib = c1 + (size_t)n*32*2080;
    const float* wb = w + oc*512;
    for (int ic=0; ic<32; ++ic){
        const float* ip = ib + ic*2080;
        const float* wp = wb + ic*16;
        #pragma unroll
        for (int kh=0; kh<4; ++kh){
            int iy = oh*2 - 2 + kh;
            if (iy < 0 || iy >= 52) continue;
            const float* irow = ip + iy*40;
            const float* wrow = wp + kh*4;
            #pragma unroll
            for (int kw=0; kw<4; ++kw){
                int ix = ow*2 - 1 + kw;
                if (ix >= 0 && ix < 40) acc += irow[ix]*wrow[kw];
            }
        }
    }
    out[idx] = acc;
}

// ---------------- spatial basis S[540][64] (f64 for exactness vs numpy)
__global__ void sbasisk(float* __restrict__ S){
    int idx = blockIdx.x*256 + threadIdx.x;
    if (idx >= P_*64) return;
    int s = idx & 63, p = idx >> 6;
    int y = p/20, x = p%20;
    int u = s >> 3, v = s & 7;
    double a  = cos((double)((y+1)*(u+1)) * M_PI / 27.0);
    double bb = cos((double)((x+1)*(v+1)) * M_PI / 20.0);
    S[idx] = (float)(a*bb);
}

// ---------------- generic transpose (R,C) -> out[c*R+r]
__global__ void transk(const float* __restrict__ in, float* __restrict__ out, int R, int C){
    int idx = blockIdx.x*256 + threadIdx.x;
    if (idx >= R*C) return;
    int r = idx / C, c = idx % C;
    out[(size_t)c*R + r] = in[idx];
}

// ---------------- ConvLSTM gates: full 192ch 3x3 conv per step
// grid: 16 b * 64 ggrp (8 gates each), block 256 threads over positions
__global__ __launch_bounds__(256) void gatesk(const float* __restrict__ x,     // conv2out (512,64,540)
                                              const float* __restrict__ hprev, // (16,128,540)
                                              const float* __restrict__ wT,    // (1728,512)
                                              const float* __restrict__ bias,  // (512)
                                              const unsigned char* __restrict__ done,
                                              float* __restrict__ gates,       // (16,512,540)
                                              int t){
    int b    = blockIdx.x >> 6;
    int ggrp = blockIdx.x & 63;
    int g0   = ggrp * 8;
    float m = done[t*B_+b] ? 0.0f : 1.0f;
    const float* xb = x + ((size_t)(t*B_+b))*64*P_;
    const float* hb = hprev + (size_t)b*128*P_;
    for (int p = threadIdx.x; p < P_; p += 256){
        int y = p/20, xx = p%20;
        int offs[9]; float vmask[9];
        {
            int q = 0;
            #pragma unroll
            for (int ky=0; ky<3; ++ky){
                int iy = y-1+ky;
                #pragma unroll
                for (int kx=0; kx<3; ++kx){
                    int ix = xx-1+kx;
                    bool ok = (iy>=0 && iy<HH && ix>=0 && ix<WW);
                    offs[q]  = ok ? iy*20+ix : 0;
                    vmask[q] = ok ? 1.0f : 0.0f;
                    ++q;
                }
            }
        }
        float acc[8];
        #pragma unroll
        for (int j=0;j<8;j++) acc[j] = bias[g0+j];
        // x channels 0..63
        for (int c=0; c<64; ++c){
            const float* src = xb + c*P_;
            const float* wrow = wT + (size_t)c*9*512 + g0;
            #pragma unroll
            for (int q=0; q<9; ++q){
                float v = src[offs[q]] * vmask[q];
                const float4 w0 = *((const float4*)(wrow + q*512));
                const float4 w1 = *((const float4*)(wrow + q*512 + 4));
                acc[0] += v*w0.x; acc[1] += v*w0.y; acc[2] += v*w0.z; acc[3] += v*w0.w;
                acc[4] += v*w1.x; acc[5] += v*w1.y; acc[6] += v*w1.z; acc[7] += v*w1.w;
            }
        }
        // h channels 64..191 (masked by m)
        #pragma unroll
        for (int q=0;q<9;q++) vmask[q] *= m;
        for (int c=0; c<128; ++c){
            const float* src = hb + c*P_;
            const float* wrow = wT + (size_t)(64+c)*9*512 + g0;
            #pragma unroll
            for (int q=0; q<9; ++q){
                float v = src[offs[q]] * vmask[q];
                const float4 w0 = *((const float4*)(wrow + q*512));
                const float4 w1 = *((const float4*)(wrow + q*512 + 4));
                acc[0] += v*w0.x; acc[1] += v*w0.y; acc[2] += v*w0.z; acc[3] += v*w0.w;
                acc[4] += v*w1.x; acc[5] += v*w1.y; acc[6] += v*w1.z; acc[7] += v*w1.w;
            }
        }
        float* gout = gates + (size_t)b*512*P_;
        #pragma unroll
        for (int j=0;j<8;j++) gout[(g0+j)*P_ + p] = acc[j];
    }
}

// ---------------- vis LSTM pointwise update + reinterpret-scatter into h_re
__global__ __launch_bounds__(256) void visupdk(const float* __restrict__ gates,
                                               const unsigned char* __restrict__ done,
                                               float* __restrict__ vh, float* __restrict__ vc,
                                               float* __restrict__ hre, int t){
    int idx = blockIdx.x*256 + threadIdx.x;   // 16*128*540 = 1,105,920 exact
    int p = idx % P_;
    int c = (idx/P_) & 127;
    int b = idx / (P_*128);
    const float* gb = gates + (size_t)b*512*P_;
    float ai = gb[(      c)*P_ + p];
    float af = gb[(128 + c)*P_ + p];
    float ao = gb[(256 + c)*P_ + p];
    float ag = gb[(384 + c)*P_ + p];
    float m  = done[t*B_+b] ? 0.0f : 1.0f;
    float cold = vc[idx] * m;
    float cn = sigm(af)*cold + sigm(ai)*tanhf(ag);
    float hn = sigm(ao)*tanhf(cn);
    vc[idx] = cn;
    vh[idx] = hn;
    // reshape quirk: flat (c,y,x) -> (h', w', ch)
    int flat = c*P_ + p;
    int hp  = flat / 2560;
    int rem = flat % 2560;
    int wp  = rem / 128;
    int ch  = rem & 127;
    hre[((size_t)b*P_ + hp*20 + wp)*128 + ch] = hn;
}

// ---------------- q MLP (one block per b) + fill r / one-hot into answer
__global__ __launch_bounds__(256) void qmlpk(const float* __restrict__ hprev,
                                             const float* __restrict__ qw1, const float* __restrict__ qb1,
                                             const float* __restrict__ qw2, const float* __restrict__ qb2,
                                             const float* __restrict__ qw3, const float* __restrict__ qb3,
                                             const float* __restrict__ reward, const int* __restrict__ lact,
                                             float* __restrict__ qbuf, float* __restrict__ answer, int t){
    __shared__ float hs[256], q1[128], q2[288];
    int b = blockIdx.x, tid = threadIdx.x;
    hs[tid] = hprev[b*256 + tid];
    __syncthreads();
    if (tid < 128){
        float a = qb1[tid];
        for (int i=0;i<256;++i) a += hs[i]*qw1[i*128+tid];
        q1[tid] = fmaxf(a, 0.0f);
    }
    __syncthreads();
    for (int o=tid; o<288; o+=256){
        float a = qb2[o];
        for (int i=0;i<128;++i) a += q1[i]*qw2[i*288+o];
        q2[o] = fmaxf(a, 0.0f);
    }
    __syncthreads();
    for (int o=tid; o<288; o+=256){
        float a = qb3[o];
        for (int i=0;i<288;++i) a += q2[i]*qw3[i*288+o];
        qbuf[b*288+o] = a;
        answer[b*1043 + 736 + o] = a;
    }
    if (tid == 0){
        float r = reward[t*B_+b];
        answer[b*1043 + 1024] = fminf(1.0f, fmaxf(-1.0f, r));
    }
    if (tid < NA) answer[b*1043 + 1025 + tid] = (lact[t*B_+b] == tid) ? 1.0f : 0.0f;
}

// ---------------- attention: one block per (b,qi)
__global__ __launch_bounds__(256) void attnk(const float* __restrict__ qbuf,
                                             const float* __restrict__ hre,
                                             const float* __restrict__ S,
                                             float* __restrict__ answer){
    int b = blockIdx.x >> 2, qi = blockIdx.x & 3, tid = threadIdx.x;
    __shared__ float qs[72];
    __shared__ float logit[P_];
    __shared__ float red[8];
    if (tid < 72) qs[tid] = qbuf[(b*4+qi)*72 + tid];
    __syncthreads();
    for (int p=tid; p<P_; p+=256){
        const float* hp = hre + ((size_t)b*P_ + p)*128;
        float a = 0.0f;
        #pragma unroll
        for (int k=0;k<8;k++) a += hp[k]*qs[k];
        const float* Sp = S + p*64;
        #pragma unroll 8
        for (int s=0;s<64;s++) a += Sp[s]*qs[8+s];
        logit[p] = a;
    }
    __syncthreads();
    float vmax = -1e30f;
    for (int p=tid; p<P_; p+=256) vmax = fmaxf(vmax, logit[p]);
    for (int off=32; off; off>>=1) vmax = fmaxf(vmax, __shfl_down(vmax, off));
    if ((tid & 63) == 0) red[tid>>6] = vmax;
    __syncthreads();
    if (tid == 0){ float mm = red[0]; for (int i=1;i<4;i++) mm = fmaxf(mm, red[i]); red[0] = mm; }
    __syncthreads();
    float mx = red[0];
    float lsum = 0.0f;
    for (int p=tid; p<P_; p+=256){ float e = expf(logit[p]-mx); logit[p] = e; lsum += e; }
    for (int off=32; off; off>>=1) lsum += __shfl_down(lsum, off);
    if ((tid & 63) == 0) red[4 + (tid>>6)] = lsum;
    __syncthreads();
    if (tid == 0) red[4] = red[4]+red[5]+red[6]+red[7];
    __syncthreads();
    float inv = 1.0f / red[4];
    for (int v=tid; v<184; v+=256){
        float a = 0.0f;
        if (v < 120){
            const float* base = hre + (size_t)b*P_*128 + 8 + v;
            for (int p=0; p<P_; ++p) a += logit[p]*base[(size_t)p*128];
        } else {
            const float* base = S + (v-120);
            for (int p=0; p<P_; ++p) a += logit[p]*base[p*64];
        }
        answer[b*1043 + qi*184 + v] = a*inv;
    }
}

// ---------------- answer MLP: one block per b, 512 threads
__global__ __launch_bounds__(512) void amlpk(const float* __restrict__ answer,
                                             const float* __restrict__ aw1, const float* __restrict__ ab1,
                                             const float* __restrict__ aw2, const float* __restrict__ ab2,
                                             float* __restrict__ ci){
    __shared__ float ans[1043];
    __shared__ float hid[512];
    int b = blockIdx.x, tid = threadIdx.x;
    for (int i=tid; i<1043; i+=512) ans[i] = answer[b*1043+i];
    __syncthreads();
    float a = ab1[tid];
    for (int i=0;i<1043;++i) a += ans[i]*aw1[(size_t)i*512 + tid];
    hid[tid] = fmaxf(a, 0.0f);
    __syncthreads();
    if (tid < 256){
        float o = ab2[tid];
        for (int j=0;j<512;++j) o += hid[j]*aw2[j*256 + tid];
        ci[b*256+tid] = o;
    }
}

// ---------------- core LSTM: grid 64 = (b, unit-chunk of 64), 256 threads
__global__ __launch_bounds__(256) void corelstmk(const float* __restrict__ ci,
                                                 const float* __restrict__ hprev,
                                                 float* __restrict__ ccur,
                                                 const float* __restrict__ wihT,  // (256,1024)
                                                 const float* __restrict__ whhT,  // (256,1024)
                                                 const float* __restrict__ bih, const float* __restrict__ bhh,
                                                 const unsigned char* __restrict__ done,
                                                 float* __restrict__ outs, int t){
    int b = blockIdx.x >> 2, chunk = blockIdx.x & 3, tid = threadIdx.x;
    __shared__ float cis[256], hs[256], gsm[256];
    float m = done[t*B_+b] ? 0.0f : 1.0f;
    cis[tid] = ci[b*256+tid];
    hs[tid]  = hprev[b*256+tid]*m;
    __syncthreads();
    int gate = tid >> 6;            // 0..3 -> i,f,g,o
    int u = chunk*64 + (tid & 63);
    int g = gate*256 + u;
    float a = bih[g] + bhh[g];
    for (int j=0;j<256;++j) a += cis[j]*wihT[j*1024+g] + hs[j]*whhT[j*1024+g];
    gsm[tid] = a;
    __syncthreads();
    if (tid < 64){
        int uu = chunk*64 + tid;
        float gi = gsm[tid], gf = gsm[64+tid], gg = gsm[128+tid], go = gsm[192+tid];
        float cold = ccur[b*256+uu]*m;
        float cn = sigm(gf)*cold + sigm(gi)*tanhf(gg);
        float hn = sigm(go)*tanhf(cn);
        ccur[b*256+uu] = cn;
        outs[(t*B_+b)*256 + uu] = hn;
    }
}

// ---------------- heads: one block per (t,b) row
__global__ __launch_bounds__(64) void finalk(const float* __restrict__ outs,
                                             const float* __restrict__ pw, const float* __restrict__ pb,
                                             const float* __restrict__ vw, const float* __restrict__ vb,
                                             float* __restrict__ dout){
    int row = blockIdx.x, tid = threadIdx.x;
    __shared__ float os[256];
    __shared__ float lg[NA];
    for (int i=tid; i<256; i+=64) os[i] = outs[row*256+i];
    __syncthreads();
    if (tid < NA){
        float a = pb[tid];
        for (int i=0;i<256;++i) a += os[i]*pw[i*NA+tid];
        lg[tid] = a;
        dout[row*NA + tid] = a;
    } else if (tid == 32){
        float a = vb[0];
        for (int i=0;i<256;++i) a += os[i]*vw[i];
        dout[9216 + row] = a;
    }
    __syncthreads();
    if (tid == 0){
        int am = 0; float bv = lg[0];
        for (int j=1;j<NA;++j) if (lg[j] > bv){ bv = lg[j]; am = j; }
        dout[9728 + row] = (float)am;
    }
}

extern "C" void kernel_launch(void* const* d_in, const int* in_sizes, int n_in,
                              void* d_out, int out_size, void* d_ws, size_t ws_size,
                              hipStream_t stream) {
    const float* frame   = (const float*)d_in[0];
    const unsigned char* done = (const unsigned char*)d_in[1];
    const int*   lact    = (const int*)d_in[2];
    const float* reward  = (const float*)d_in[3];
    const float* core_h0 = (const float*)d_in[4];
    const float* core_c0 = (const float*)d_in[5];
    const float* conv_h0 = (const float*)d_in[6];
    const float* conv_c0 = (const float*)d_in[7];
    const float* cnn_w1  = (const float*)d_in[8];
    const float* cnn_b1  = (const float*)d_in[9];
    const float* cnn_w2  = (const float*)d_in[10];
    const float* cnn_b2  = (const float*)d_in[11];
    const float* lstm_w  = (const float*)d_in[12];
    const float* lstm_b  = (const float*)d_in[13];
    const float* qw1 = (const float*)d_in[14]; const float* qb1 = (const float*)d_in[15];
    const float* qw2 = (const float*)d_in[16]; const float* qb2 = (const float*)d_in[17];
    const float* qw3 = (const float*)d_in[18]; const float* qb3 = (const float*)d_in[19];
    const float* aw1 = (const float*)d_in[20]; const float* ab1 = (const float*)d_in[21];
    const float* aw2 = (const float*)d_in[22]; const float* ab2 = (const float*)d_in[23];
    const float* w_ih = (const float*)d_in[24]; const float* w_hh = (const float*)d_in[25];
    const float* b_ih = (const float*)d_in[26]; const float* b_hh = (const float*)d_in[27];
    const float* pw = (const float*)d_in[28]; const float* pb = (const float*)d_in[29];
    const float* vw = (const float*)d_in[30]; const float* vb = (const float*)d_in[31];

    float* ws = (float*)d_ws;
    float* dout = (float*)d_out;

    // ws layout (floats)
    const size_t off_c2   = 0;              // 17,694,720
    const size_t off_s    = 17694720;       // 34,560
    const size_t off_vh   = 17729280;       // 1,105,920
    const size_t off_vc   = 18835200;       // 1,105,920
    const size_t off_hre  = 19941120;       // 1,105,920
    const size_t off_g    = 21047040;       // 4,423,680
    const size_t off_wT   = 25470720;       // 884,736
    const size_t off_q    = 26355456;       // 4,608
    const size_t off_ans  = 26360064;       // 16,688
    const size_t off_ci   = 26376752;       // 4,096
    const size_t off_cc   = 26380848;       // 4,096
    const size_t off_outs = 26384944;       // 131,072
    const size_t off_wihT = 26516016;       // 262,144
    const size_t off_whhT = 26778160;       // 262,144
    // conv1 scratch overlaps the post-conv region (dead after conv2k)
    const size_t off_c1   = 17694720;       // 34,078,720 -> end 51,773,440 floats (~198 MiB)

    float* c2   = ws + off_c2;
    float* c1   = ws + off_c1;
    float* S    = ws + off_s;
    float* vh   = ws + off_vh;
    float* vc   = ws + off_vc;
    float* hre  = ws + off_hre;
    float* gbuf = ws + off_g;
    float* wT   = ws + off_wT;
    float* qbuf = ws + off_q;
    float* ansb = ws + off_ans;
    float* cib  = ws + off_ci;
    float* ccb  = ws + off_cc;
    float* outs = ws + off_outs;
    float* wihT = ws + off_wihT;
    float* whhT = ws + off_whhT;

    // CNN (conv1 scratch is only live between these two)
    conv1k<<<133120, 256, 0, stream>>>(frame, cnn_w1, cnn_b1, c1);
    conv2k<<<69120, 256, 0, stream>>>(c1, cnn_w2, cnn_b2, c2);

    // constants (after conv1 scratch is dead)
    sbasisk<<<135, 256, 0, stream>>>(S);
    transk<<<3456, 256, 0, stream>>>(lstm_w, wT, 512, 1728);
    transk<<<1024, 256, 0, stream>>>(w_ih, wihT, 1024, 256);
    transk<<<1024, 256, 0, stream>>>(w_hh, whhT, 1024, 256);

    // initial states
    hipMemcpyAsync(vh,  conv_h0, (size_t)16*128*540*sizeof(float), hipMemcpyDeviceToDevice, stream);
    hipMemcpyAsync(vc,  conv_c0, (size_t)16*128*540*sizeof(float), hipMemcpyDeviceToDevice, stream);
    hipMemcpyAsync(ccb, core_c0, (size_t)16*256*sizeof(float),     hipMemcpyDeviceToDevice, stream);

    for (int t = 0; t < T_; ++t){
        gatesk<<<1024, 256, 0, stream>>>(c2, vh, wT, lstm_b, done, gbuf, t);
        visupdk<<<4320, 256, 0, stream>>>(gbuf, done, vh, vc, hre, t);
        const float* hprev = (t == 0) ? core_h0 : (outs + (size_t)(t-1)*B_*256);
        qmlpk<<<16, 256, 0, stream>>>(hprev, qw1, qb1, qw2, qb2, qw3, qb3, reward, lact, qbuf, ansb, t);
        attnk<<<64, 256, 0, stream>>>(qbuf, hre, S, ansb);
        amlpk<<<16, 512, 0, stream>>>(ansb, aw1, ab1, aw2, ab2, cib);
        corelstmk<<<64, 256, 0, stream>>>(cib, hprev, ccb, wihT, whhT, b_ih, b_hh, done, outs, t);
    }

    finalk<<<512, 64, 0, stream>>>(outs, pw, pb, vw, vb, dout);

    // trailing state outputs: ch, cc, vh, vc
    hipMemcpyAsync(dout + 10240,  outs + (size_t)(T_-1)*B_*256, (size_t)16*256*sizeof(float), hipMemcpyDeviceToDevice, stream);
    hipMemcpyAsync(dout + 14336,  ccb, (size_t)16*256*sizeof(float), hipMemcpyDeviceToDevice, stream);
    hipMemcpyAsync(dout + 18432,  vh,  (size_t)16*128*540*sizeof(float), hipMemcpyDeviceToDevice, stream);
    hipMemcpyAsync(dout + 1124352, vc, (size_t)16*128*540*sizeof(float), hipMemcpyDeviceToDevice, stream);
}

// Round 2
// 14150.572 us; speedup vs baseline: 2.3166x; 2.3166x over previous
//
#include <hip/hip_runtime.h>
#include <math.h>

#define T_ 32
#define B_ 16
#define NA 18
#define P_ 540   // 27*20

__device__ __forceinline__ float sigm(float x){ return 1.0f/(1.0f+expf(-x)); }

// ---------------- conv1: (512,3,210,160) -> (512,32,52,40), k8 s4 pad H(1,1) W(2,2)
// block per (n, oh): LDS-stage 3ch x 8 rows x 168 padded cols
__global__ __launch_bounds__(256) void conv1k(const float* __restrict__ frame,
                                              const float* __restrict__ w,
                                              const float* __restrict__ bias,
                                              float* __restrict__ out){
    __shared__ float tile[4032];  // 3*8*168
    int bid = blockIdx.x;
    int n = bid / 52, oh = bid % 52;
    int tid = threadIdx.x;
    const float* fb = frame + (size_t)n*3*210*160;
    for (int s = tid; s < 4032; s += 256){
        int col = s % 168;
        int row = (s/168) & 7;
        int ic  = s / 1344;
        int iy = oh*4 - 1 + row;
        int ix = col - 2;
        float v = 0.f;
        if (iy >= 0 && iy < 210 && ix >= 0 && ix < 160) v = fb[ic*33600 + iy*160 + ix];
        tile[s] = v;
    }
    __syncthreads();
    float* ob = out + (size_t)n*66560 + oh*40;
    for (int k=0;k<5;++k){
        int idx = tid + 256*k;      // 0..1279 : 32 oc x 40 ow
        int oc = idx / 40, ow = idx % 40;
        float acc = bias[oc];
        const float* wb = w + oc*192;
        for (int ic=0; ic<3; ++ic){
            #pragma unroll
            for (int kh=0; kh<8; ++kh){
                const float* lrow = tile + ic*1344 + kh*168 + ow*4;  // col = ow*4+kw
                const float* wr = wb + ic*64 + kh*8;
                float4 w0 = *((const float4*)wr);
                float4 w1 = *((const float4*)(wr+4));
                acc += lrow[0]*w0.x + lrow[1]*w0.y + lrow[2]*w0.z + lrow[3]*w0.w
                     + lrow[4]*w1.x + lrow[5]*w1.y + lrow[6]*w1.z + lrow[7]*w1.w;
            }
        }
        ob[(size_t)oc*2080 + ow] = acc;
    }
}

// ---------------- conv2: (512,32,52,40) -> (512,64,27,20), k4 s2 pad H(2,2) W(1,1)
// block per (n, oh): LDS-stage 32ch x 4 rows x 42 padded cols
__global__ __launch_bounds__(256) void conv2k(const float* __restrict__ c1,
                                              const float* __restrict__ w,
                                              const float* __restrict__ bias,
                                              float* __restrict__ out){
    __shared__ float tile[5376];  // 32*4*42
    int bid = blockIdx.x;
    int n = bid / 27, oh = bid % 27;
    int tid = threadIdx.x;
    const float* ib = c1 + (size_t)n*66560;
    for (int s = tid; s < 5376; s += 256){
        int col = s % 42;
        int row = (s/42) & 3;
        int ic  = s / 168;
        int iy = oh*2 - 2 + row;
        int ix = col - 1;
        float v = 0.f;
        if (iy >= 0 && iy < 52 && ix >= 0 && ix < 40) v = ib[ic*2080 + iy*40 + ix];
        tile[s] = v;
    }
    __syncthreads();
    float* ob = out + (size_t)n*64*540 + oh*20;
    for (int k=0;k<5;++k){
        int idx = tid + 256*k;     // 0..1279 : 64 oc x 20 ow
        int oc = idx / 20, ow = idx % 20;
        float acc = bias[oc];
        const float* wb = w + oc*512;
        for (int ic=0; ic<32; ++ic){
            const float* lp = tile + ic*168 + ow*2;   // col = ow*2+kw
            const float* wp = wb + ic*16;
            #pragma unroll
            for (int kh=0; kh<4; ++kh){
                float4 w0 = *((const float4*)(wp + kh*4));
                const float* lr = lp + kh*42;
                acc += lr[0]*w0.x + lr[1]*w0.y + lr[2]*w0.z + lr[3]*w0.w;
            }
        }
        ob[(size_t)oc*540 + ow] = acc;
    }
}

// ---------------- spatial basis S[540][64]
__global__ void sbasisk(float* __restrict__ S){
    int idx = blockIdx.x*256 + threadIdx.x;
    if (idx >= P_*64) return;
    int s = idx & 63, p = idx >> 6;
    int y = p/20, x = p%20;
    int u = s >> 3, v = s & 7;
    double a  = cos((double)((y+1)*(u+1)) * M_PI / 27.0);
    double bb = cos((double)((x+1)*(v+1)) * M_PI / 20.0);
    S[idx] = (float)(a*bb);
}

// ---------------- repack lstm_w (512,192,3,3) -> wp[cc 64][ic 192][q 9][j 8]
// j = cpi*4 + gt ; gate g = gt*128 + 2*cc + cpi
__global__ void wpackk(const float* __restrict__ lw, float* __restrict__ wp){
    int o = blockIdx.x*256 + threadIdx.x;
    if (o >= 884736) return;
    int j = o & 7, q = (o>>3) % 9, ic = (o/72) % 192, cc = o / 13824;
    int cpi = j >> 2, gt = j & 3;
    int g = gt*128 + 2*cc + cpi;
    wp[o] = lw[(size_t)g*1728 + ic*9 + q];
}

// ---------------- generic transpose (R,C) -> out[c*R+r]
__global__ void transk(const float* __restrict__ in, float* __restrict__ out, int R, int C){
    int idx = blockIdx.x*256 + threadIdx.x;
    if (idx >= R*C) return;
    int r = idx / C, c = idx % C;
    out[(size_t)c*R + r] = in[idx];
}

// ---------------- fused ConvLSTM step: gates conv + pointwise update + hre scatter
// grid: 16 b * 64 cc (channel pairs), 192 threads (3 positions each)
__global__ __launch_bounds__(192) void glstmk(const float* __restrict__ x,     // c2 (512,64,540)
                                              const float* __restrict__ hin,   // (16,128,540)
                                              float* __restrict__ hout,        // (16,128,540)
                                              float* __restrict__ vc,          // (16,128,540)
                                              const float* __restrict__ wp,    // packed weights
                                              const float* __restrict__ bias,  // (512)
                                              const unsigned char* __restrict__ done,
                                              float* __restrict__ hre,         // (16,540,128)
                                              int t){
    __shared__ float plane[2][640];   // 29x22 zero-padded plane, double-buffered
    const int QOFF[9] = {0,1,2,22,23,24,44,45,46};
    int bid = blockIdx.x;
    int b = bid >> 6, cc = bid & 63;
    int tid = threadIdx.x;
    float m = done[t*B_+b] ? 0.f : 1.f;
    const float* xb = x + ((size_t)(t*B_+b))*64*P_;
    const float* hb = hin + (size_t)b*128*P_;

    int p0 = tid, p1 = tid+192, p2 = tid+384;
    bool v2 = (p2 < P_);
    int p2c = v2 ? p2 : 539;
    int base0 = (p0/20)*22 + (p0%20);   // top-left of stencil in padded coords
    int base1 = (p1/20)*22 + (p1%20);
    int base2 = (p2c/20)*22 + (p2c%20);

    // zero borders of both buffers (interior gets overwritten every ic)
    for (int s = tid; s < 640; s += 192){
        int r = s / 22, c = s % 22;
        if (s >= 638 || r == 0 || r == 28 || c == 0 || c == 21){
            plane[0][s] = 0.f; plane[1][s] = 0.f;
        }
    }
    // stage plane ic=0 (x channel, unmasked)
    {
        float a0 = xb[p0], a1 = xb[p1], a2 = v2 ? xb[p2] : 0.f;
        plane[0][base0+23] = a0; plane[0][base1+23] = a1; if (v2) plane[0][base2+23] = a2;
    }
    __syncthreads();

    float acc0[8], acc1[8], acc2[8], bj[8];
    #pragma unroll
    for (int j=0;j<8;++j){
        bj[j] = bias[(j&3)*128 + 2*cc + (j>>2)];
        acc0[j]=0.f; acc1[j]=0.f; acc2[j]=0.f;
    }
    const float* wpb = wp + (size_t)cc*13824;

    for (int ic=0; ic<192; ++ic){
        int cur = ic & 1;
        float n0=0.f, n1=0.f, n2=0.f;
        if (ic < 191){
            int nic = ic+1;
            const float* src = (nic < 64) ? (xb + nic*P_) : (hb + (nic-64)*P_);
            float mm = (nic < 64) ? 1.f : m;
            n0 = src[p0]*mm; n1 = src[p1]*mm; n2 = v2 ? src[p2]*mm : 0.f;
        }
        const float* wrow = wpb + ic*72;
        const float* pl = plane[cur];
        #pragma unroll
        for (int q=0; q<9; ++q){
            float4 w0 = *((const float4*)(wrow + q*8));
            float4 w1 = *((const float4*)(wrow + q*8 + 4));
            float a = pl[base0 + QOFF[q]];
            acc0[0] += a*w0.x; acc0[1] += a*w0.y; acc0[2] += a*w0.z; acc0[3] += a*w0.w;
            acc0[4] += a*w1.x; acc0[5] += a*w1.y; acc0[6] += a*w1.z; acc0[7] += a*w1.w;
            float bv = pl[base1 + QOFF[q]];
            acc1[0] += bv*w0.x; acc1[1] += bv*w0.y; acc1[2] += bv*w0.z; acc1[3] += bv*w0.w;
            acc1[4] += bv*w1.x; acc1[5] += bv*w1.y; acc1[6] += bv*w1.z; acc1[7] += bv*w1.w;
            float cv = pl[base2 + QOFF[q]];
            acc2[0] += cv*w0.x; acc2[1] += cv*w0.y; acc2[2] += cv*w0.z; acc2[3] += cv*w0.w;
            acc2[4] += cv*w1.x; acc2[5] += cv*w1.y; acc2[6] += cv*w1.z; acc2[7] += cv*w1.w;
        }
        if (ic < 191){
            int nxt = cur^1;
            plane[nxt][base0+23] = n0; plane[nxt][base1+23] = n1; if (v2) plane[nxt][base2+23] = n2;
        }
        __syncthreads();
    }

    // epilogue: LSTM pointwise update for channels 2cc, 2cc+1 at this thread's positions
    float* vcb = vc + (size_t)b*128*P_;
    float* hob = hout + (size_t)b*128*P_;
    float* hrb = hre + (size_t)b*P_*128;
    #pragma unroll
    for (int k=0; k<3; ++k){
        if (k==2 && !v2) break;
        int p = (k==0) ? p0 : (k==1) ? p1 : p2;
        const float* A = (k==0) ? acc0 : (k==1) ? acc1 : acc2;
        #pragma unroll
        for (int cpi=0; cpi<2; ++cpi){
            int c = 2*cc + cpi;
            float gi = A[cpi*4+0] + bj[cpi*4+0];
            float gf = A[cpi*4+1] + bj[cpi*4+1];
            float go = A[cpi*4+2] + bj[cpi*4+2];
            float gg = A[cpi*4+3] + bj[cpi*4+3];
            float cold = vcb[c*P_+p]*m;
            float cn = sigm(gf)*cold + sigm(gi)*tanhf(gg);
            float hn = sigm(go)*tanhf(cn);
            vcb[c*P_+p] = cn;
            hob[c*P_+p] = hn;
            int flat = c*P_ + p;
            hrb[((flat/2560)*20 + (flat%2560)/128)*128 + (flat & 127)] = hn;
        }
    }
}

// ---------------- fused core step: qMLP + attention + answerMLP + LSTM. one block per b
__global__ __launch_bounds__(512) void corek(const float* __restrict__ hprev,
                                             const float* __restrict__ hre,
                                             const float* __restrict__ S,
                                             const float* __restrict__ qw1, const float* __restrict__ qb1,
                                             const float* __restrict__ qw2, const float* __restrict__ qb2,
                                             const float* __restrict__ qw3, const float* __restrict__ qb3,
                                             const float* __restrict__ aw1, const float* __restrict__ ab1,
                                             const float* __restrict__ aw2, const float* __restrict__ ab2,
                                             const float* __restrict__ wihT, const float* __restrict__ whhT,
                                             const float* __restrict__ bih, const float* __restrict__ bhh,
                                             const float* __restrict__ reward, const int* __restrict__ lact,
                                             const unsigned char* __restrict__ done,
                                             float* __restrict__ ccb, float* __restrict__ outs, int t){
    __shared__ float hs[256], q1[128], q2[288], q3[288];
    __shared__ float elog[4][P_];
    __shared__ float red[32];
    __shared__ float ansv[1056];
    __shared__ float hid[512];
    __shared__ float cis[256], hs2[256];
    __shared__ float gb[1024];
    int b = blockIdx.x, tid = threadIdx.x;
    if (tid < 256) hs[tid] = hprev[b*256+tid];
    __syncthreads();
    if (tid < 128){
        float a = qb1[tid];
        for (int i=0;i<256;++i) a += hs[i]*qw1[i*128+tid];
        q1[tid] = fmaxf(a,0.f);
    }
    __syncthreads();
    if (tid < 288){
        float a = qb2[tid];
        for (int i=0;i<128;++i) a += q1[i]*qw2[i*288+tid];
        q2[tid] = fmaxf(a,0.f);
    }
    __syncthreads();
    if (tid < 288){
        float a = qb3[tid];
        for (int i=0;i<288;++i) a += q2[i]*qw3[i*288+tid];
        q3[tid] = a;
        ansv[736+tid] = a;
    }
    if (tid == 0){ float r = reward[t*B_+b]; ansv[1024] = fminf(1.f,fmaxf(-1.f,r)); }
    if (tid >= 32 && tid < 32+NA) ansv[1025 + tid-32] = (lact[t*B_+b] == tid-32) ? 1.f : 0.f;
    __syncthreads();
    // logits
    const float* hrb = hre + (size_t)b*P_*128;
    for (int idx = tid; idx < 4*P_; idx += 512){
        int qi = idx / P_, p = idx % P_;
        const float* hp = hrb + (size_t)p*128;
        const float* qv = q3 + qi*72;
        float4 h0 = *((const float4*)hp);
        float4 h1 = *((const float4*)(hp+4));
        float a = h0.x*qv[0]+h0.y*qv[1]+h0.z*qv[2]+h0.w*qv[3]
                + h1.x*qv[4]+h1.y*qv[5]+h1.z*qv[6]+h1.w*qv[7];
        const float* Sp = S + p*64;
        #pragma unroll
        for (int s2=0;s2<16;++s2){
            float4 sv = *((const float4*)(Sp + 4*s2));
            a += sv.x*qv[8+4*s2] + sv.y*qv[9+4*s2] + sv.z*qv[10+4*s2] + sv.w*qv[11+4*s2];
        }
        elog[qi][p] = a;
    }
    __syncthreads();
    // softmax per qi (128 threads per qi = 2 waves)
    {
        int qi = tid >> 7, lt = tid & 127;
        float mx = -1e30f;
        for (int p = lt; p < P_; p += 128) mx = fmaxf(mx, elog[qi][p]);
        for (int off=32; off; off>>=1) mx = fmaxf(mx, __shfl_down(mx, off));
        if ((tid & 63) == 0) red[tid>>6] = mx;
        __syncthreads();
        if (tid < 4) red[16+tid] = fmaxf(red[2*tid], red[2*tid+1]);
        __syncthreads();
        mx = red[16+qi];
        float s = 0.f;
        for (int p = lt; p < P_; p += 128){ float e = expf(elog[qi][p]-mx); elog[qi][p] = e; s += e; }
        for (int off=32; off; off>>=1) s += __shfl_down(s, off);
        if ((tid & 63) == 0) red[8 + (tid>>6)] = s;
        __syncthreads();
        if (tid < 4) red[24+tid] = red[8+2*tid] + red[8+2*tid+1];
        __syncthreads();
    }
    // ans
    for (int idx = tid; idx < 736; idx += 512){
        int qi = idx / 184, v = idx % 184;
        float a = 0.f;
        if (v < 120){
            const float* basep = hrb + 8 + v;
            for (int p=0;p<P_;++p) a += elog[qi][p]*basep[(size_t)p*128];
        } else {
            const float* basep = S + (v-120);
            for (int p=0;p<P_;++p) a += elog[qi][p]*basep[p*64];
        }
        ansv[qi*184+v] = a / red[24+qi];
    }
    __syncthreads();
    // answer MLP layer1 (512 hidden)
    {
        float a = ab1[tid];
        for (int i=0;i<1043;++i) a += ansv[i]*aw1[(size_t)i*512+tid];
        hid[tid] = fmaxf(a, 0.f);
    }
    float m = done[t*B_+b] ? 0.f : 1.f;
    if (tid < 256) hs2[tid] = hs[tid]*m;
    __syncthreads();
    if (tid < 256){
        float o = ab2[tid];
        for (int j=0;j<512;++j) o += hid[j]*aw2[j*256+tid];
        cis[tid] = o;
    }
    __syncthreads();
    for (int g = tid; g < 1024; g += 512){
        float a = bih[g] + bhh[g];
        for (int j=0;j<256;++j) a += cis[j]*wihT[j*1024+g] + hs2[j]*whhT[j*1024+g];
        gb[g] = a;
    }
    __syncthreads();
    if (tid < 256){
        // core gate order: i, f, g, o
        float gi = gb[tid], gf = gb[256+tid], gg = gb[512+tid], go = gb[768+tid];
        float cold = ccb[b*256+tid]*m;
        float cn = sigm(gf)*cold + sigm(gi)*tanhf(gg);
        float hn = sigm(go)*tanhf(cn);
        ccb[b*256+tid] = cn;
        outs[(t*B_+b)*256+tid] = hn;
    }
}

// ---------------- heads
__global__ __launch_bounds__(64) void finalk(const float* __restrict__ outs,
                                             const float* __restrict__ pw, const float* __restrict__ pb,
                                             const float* __restrict__ vw, const float* __restrict__ vb,
                                             float* __restrict__ dout){
    int row = blockIdx.x, tid = threadIdx.x;
    __shared__ float os[256];
    __shared__ float lg[NA];
    for (int i=tid; i<256; i+=64) os[i] = outs[row*256+i];
    __syncthreads();
    if (tid < NA){
        float a = pb[tid];
        for (int i=0;i<256;++i) a += os[i]*pw[i*NA+tid];
        lg[tid] = a;
        dout[row*NA + tid] = a;
    } else if (tid == 32){
        float a = vb[0];
        for (int i=0;i<256;++i) a += os[i]*vw[i];
        dout[9216 + row] = a;
    }
    __syncthreads();
    if (tid == 0){
        int am = 0; float bv = lg[0];
        for (int j=1;j<NA;++j) if (lg[j] > bv){ bv = lg[j]; am = j; }
        dout[9728 + row] = (float)am;
    }
}

extern "C" void kernel_launch(void* const* d_in, const int* in_sizes, int n_in,
                              void* d_out, int out_size, void* d_ws, size_t ws_size,
                              hipStream_t stream) {
    const float* frame   = (const float*)d_in[0];
    const unsigned char* done = (const unsigned char*)d_in[1];
    const int*   lact    = (const int*)d_in[2];
    const float* reward  = (const float*)d_in[3];
    const float* core_h0 = (const float*)d_in[4];
    const float* core_c0 = (const float*)d_in[5];
    const float* conv_h0 = (const float*)d_in[6];
    const float* conv_c0 = (const float*)d_in[7];
    const float* cnn_w1  = (const float*)d_in[8];
    const float* cnn_b1  = (const float*)d_in[9];
    const float* cnn_w2  = (const float*)d_in[10];
    const float* cnn_b2  = (const float*)d_in[11];
    const float* lstm_w  = (const float*)d_in[12];
    const float* lstm_b  = (const float*)d_in[13];
    const float* qw1 = (const float*)d_in[14]; const float* qb1 = (const float*)d_in[15];
    const float* qw2 = (const float*)d_in[16]; const float* qb2 = (const float*)d_in[17];
    const float* qw3 = (const float*)d_in[18]; const float* qb3 = (const float*)d_in[19];
    const float* aw1 = (const float*)d_in[20]; const float* ab1 = (const float*)d_in[21];
    const float* aw2 = (const float*)d_in[22]; const float* ab2 = (const float*)d_in[23];
    const float* w_ih = (const float*)d_in[24]; const float* w_hh = (const float*)d_in[25];
    const float* b_ih = (const float*)d_in[26]; const float* b_hh = (const float*)d_in[27];
    const float* pw = (const float*)d_in[28]; const float* pb = (const float*)d_in[29];
    const float* vw = (const float*)d_in[30]; const float* vb = (const float*)d_in[31];

    float* ws = (float*)d_ws;
    float* dout = (float*)d_out;

    // ws layout (floats). c1 is transient; everything after off 17,694,720 is
    // written only after conv2k completes (stream-ordered), so it may overlap c1.
    float* c2    = ws;                 // 17,694,720
    float* c1    = ws + 17694720;      // 34,078,720 (transient; footprint to 51,773,440)
    float* S     = ws + 17694720;      // 34,560
    float* vha   = ws + 17729280;      // 1,105,920
    float* vhb   = ws + 18835200;      // 1,105,920
    float* vcb   = ws + 19941120;      // 1,105,920
    float* hre   = ws + 21047040;      // 1,105,920
    float* wpack = ws + 22152960;      // 884,736
    float* wihT  = ws + 23037696;      // 262,144
    float* whhT  = ws + 23299840;      // 262,144
    float* outs  = ws + 23561984;      // 131,072
    float* ccb   = ws + 23693056;      // 4,096

    // CNN
    conv1k<<<512*52, 256, 0, stream>>>(frame, cnn_w1, cnn_b1, c1);
    conv2k<<<512*27, 256, 0, stream>>>(c1, cnn_w2, cnn_b2, c2);

    // constants (after c1 is dead)
    sbasisk<<<135, 256, 0, stream>>>(S);
    wpackk<<<3456, 256, 0, stream>>>(lstm_w, wpack);
    transk<<<1024, 256, 0, stream>>>(w_ih, wihT, 1024, 256);
    transk<<<1024, 256, 0, stream>>>(w_hh, whhT, 1024, 256);

    // initial states
    hipMemcpyAsync(vha, conv_h0, (size_t)16*128*540*sizeof(float), hipMemcpyDeviceToDevice, stream);
    hipMemcpyAsync(vcb, conv_c0, (size_t)16*128*540*sizeof(float), hipMemcpyDeviceToDevice, stream);
    hipMemcpyAsync(ccb, core_c0, (size_t)16*256*sizeof(float),     hipMemcpyDeviceToDevice, stream);

    for (int t = 0; t < T_; ++t){
        const float* hin = (t & 1) ? vhb : vha;
        float* hout      = (t & 1) ? vha : vhb;
        glstmk<<<1024, 192, 0, stream>>>(c2, hin, hout, vcb, wpack, lstm_b, done, hre, t);
        const float* hprev = (t == 0) ? core_h0 : (outs + (size_t)(t-1)*B_*256);
        corek<<<16, 512, 0, stream>>>(hprev, hre, S, qw1,qb1,qw2,qb2,qw3,qb3,
                                      aw1,ab1,aw2,ab2, wihT,whhT,b_ih,b_hh,
                                      reward, lact, done, ccb, outs, t);
    }

    finalk<<<512, 64, 0, stream>>>(outs, pw, pb, vw, vb, dout);

    // trailing state outputs: ch, cc, vh (in vha after t=31), vc
    hipMemcpyAsync(dout + 10240,   outs + (size_t)31*B_*256, (size_t)16*256*sizeof(float), hipMemcpyDeviceToDevice, stream);
    hipMemcpyAsync(dout + 14336,   ccb, (size_t)16*256*sizeof(float), hipMemcpyDeviceToDevice, stream);
    hipMemcpyAsync(dout + 18432,   vha, (size_t)16*128*540*sizeof(float), hipMemcpyDeviceToDevice, stream);
    hipMemcpyAsync(dout + 1124352, vcb, (size_t)16*128*540*sizeof(float), hipMemcpyDeviceToDevice, stream);
}

// Round 3
// 10446.483 us; speedup vs baseline: 3.1380x; 1.3546x over previous
//
#include <hip/hip_runtime.h>
#include <math.h>

#define T_ 32
#define B_ 16
#define NA 18
#define P_ 540   // 27*20
#define NB 9     // N-blocks of 64 cols over 544-padded N per b

typedef __attribute__((ext_vector_type(8)))  short short8;
typedef __attribute__((ext_vector_type(16))) float f32x16;

__device__ __forceinline__ float sigm(float x){ return 1.0f/(1.0f+expf(-x)); }
__device__ __forceinline__ unsigned short f2bf(float f){
    unsigned u = __float_as_uint(f);
    u += 0x7fff + ((u>>16)&1u);
    return (unsigned short)(u>>16);
}

// ---------------- conv1: (512,3,210,160) -> c1 (512,32,52,40), k8 s4 padH(1,1) W(2,2)
// lanes = oc (broadcast LDS reads), 5 ow per thread
__global__ __launch_bounds__(256) void conv1k(const float* __restrict__ frame,
                                              const float* __restrict__ w,
                                              const float* __restrict__ bias,
                                              float* __restrict__ out){
    __shared__ float tile[4032];  // 3ch * 8rows * 168cols (padded)
    int bid = blockIdx.x;
    int n = bid / 52, oh = bid % 52;
    int tid = threadIdx.x;
    const float* fb = frame + (size_t)n*3*210*160;
    for (int s = tid; s < 4032; s += 256){
        int col = s % 168;
        int row = (s/168) & 7;
        int ic  = s / 1344;
        int iy = oh*4 - 1 + row;
        int ix = col - 2;
        float v = 0.f;
        if (iy >= 0 && iy < 210 && ix >= 0 && ix < 160) v = fb[ic*33600 + iy*160 + ix];
        tile[s] = v;
    }
    __syncthreads();
    int oc = tid & 31, grp = tid >> 5;      // grp 0..7 -> ow = grp*5..grp*5+4
    float acc[5] = {0.f,0.f,0.f,0.f,0.f};
    const float* wb = w + oc*192;
    for (int ic=0; ic<3; ++ic){
        #pragma unroll
        for (int kh=0; kh<8; ++kh){
            const float* wr = wb + ic*64 + kh*8;
            float4 w0 = *((const float4*)wr);
            float4 w1 = *((const float4*)(wr+4));
            const float* row = tile + ic*1344 + kh*168;
            #pragma unroll
            for (int o=0;o<5;++o){
                const float* r = row + (grp*5+o)*4;
                acc[o] += r[0]*w0.x + r[1]*w0.y + r[2]*w0.z + r[3]*w0.w
                        + r[4]*w1.x + r[5]*w1.y + r[6]*w1.z + r[7]*w1.w;
            }
        }
    }
    float* ob = out + (size_t)n*66560 + (size_t)oc*2080 + oh*40;
    float bi = bias[oc];
    #pragma unroll
    for (int o=0;o<5;++o) ob[grp*5+o] = acc[o] + bi;
}

// ---------------- conv2: c1 -> xpad bf16 padded planes [512][64][640], k4 s2 padH(2,2) W(1,1)
// lanes = oc (broadcast LDS reads), 5 ow per thread
__global__ __launch_bounds__(256) void conv2k(const float* __restrict__ c1,
                                              const float* __restrict__ w,
                                              const float* __restrict__ bias,
                                              unsigned short* __restrict__ xpad){
    __shared__ float tile[5376];  // 32ch * 4rows * 42cols (padded)
    int bid = blockIdx.x;
    int s = bid / 27, oh = bid % 27;
    int tid = threadIdx.x;
    const float* ib = c1 + (size_t)s*66560;
    for (int q = tid; q < 5376; q += 256){
        int col = q % 42;
        int row = (q/42) & 3;
        int ic  = q / 168;
        int iy = oh*2 - 2 + row;
        int ix = col - 1;
        float v = 0.f;
        if (iy >= 0 && iy < 52 && ix >= 0 && ix < 40) v = ib[ic*2080 + iy*40 + ix];
        tile[q] = v;
    }
    __syncthreads();
    int oc = tid & 63, grp = tid >> 6;      // grp 0..3 -> ow = grp*5..grp*5+4
    float acc[5] = {0.f,0.f,0.f,0.f,0.f};
    const float* wb = w + oc*512;
    for (int ic=0; ic<32; ++ic){
        const float* wp = wb + ic*16;
        float4 w0 = *((const float4*)wp);
        float4 w1 = *((const float4*)(wp+4));
        float4 w2 = *((const float4*)(wp+8));
        float4 w3 = *((const float4*)(wp+12));
        const float* tp = tile + ic*168;
        #pragma unroll
        for (int o=0;o<5;++o){
            const float* r = tp + (grp*5+o)*2;
            acc[o] += r[0]*w0.x    + r[1]*w0.y    + r[2]*w0.z    + r[3]*w0.w
                    + r[42]*w1.x   + r[43]*w1.y   + r[44]*w1.z   + r[45]*w1.w
                    + r[84]*w2.x   + r[85]*w2.y   + r[86]*w2.z   + r[87]*w2.w
                    + r[126]*w3.x  + r[127]*w3.y  + r[128]*w3.z  + r[129]*w3.w;
        }
    }
    float bi = bias[oc];
    unsigned short* op = xpad + ((size_t)s*64 + oc)*640 + (oh+1)*22 + 1;
    #pragma unroll
    for (int o=0;o<5;++o) op[grp*5+o] = f2bf(acc[o] + bi);
}

// ---------------- spatial basis S[540][64]
__global__ void sbasisk(float* __restrict__ S){
    int idx = blockIdx.x*256 + threadIdx.x;
    if (idx >= P_*64) return;
    int s = idx & 63, p = idx >> 6;
    int y = p/20, x = p%20;
    int u = s >> 3, v = s & 7;
    double a  = cos((double)((y+1)*(u+1)) * M_PI / 27.0);
    double bb = cos((double)((x+1)*(v+1)) * M_PI / 20.0);
    S[idx] = (float)(a*bb);
}

// ---------------- generic transpose (R,C) -> out[c*R+r]
__global__ void transk(const float* __restrict__ in, float* __restrict__ out, int R, int C){
    int idx = blockIdx.x*256 + threadIdx.x;
    if (idx >= R*C) return;
    int r = idx / C, c = idx % C;
    out[(size_t)c*R + r] = in[idx];
}

// ---------------- A-fragment prepack: lstm_w (512,192,3,3) -> apack[192][16][64][8] bf16
// chunk ch (=concat channel), mtile mt, lane, j:  A[m=mt*32+(lane&31)][k=(lane>>5)*8+j], k>=9 -> 0
__global__ void apackk(const float* __restrict__ lw, unsigned short* __restrict__ ap){
    int idx = blockIdx.x*256 + threadIdx.x;
    if (idx >= 1572864) return;
    int j = idx & 7;
    int lane = (idx>>3) & 63;
    int mt = (idx>>9) & 15;
    int ch = idx >> 13;
    int kk = ((lane>>5)<<3) + j;
    int oc = mt*32 + (lane & 31);
    ap[idx] = (kk < 9) ? f2bf(lw[(size_t)oc*1728 + ch*9 + kk]) : (unsigned short)0;
}

// ---------------- pack conv_h0 fp32 -> hpad bf16 interior
__global__ void h0packk(const float* __restrict__ h0, unsigned short* __restrict__ hpad){
    int idx = blockIdx.x*256 + threadIdx.x;
    if (idx >= 16*128*540) return;
    int plane = idx / 540, p = idx % 540;
    hpad[(size_t)plane*640 + (p/20+1)*22 + (p%20) + 1] = f2bf(h0[idx]);
}

// ---------------- gates GEMM: gates[b][oc][544] = sum_k W.x/h  (bf16 MFMA 32x32x16)
// grid 288 = 16b * 9nb * 2mh ; 256 threads = 4 waves; wave covers M=64 (2 tiles) x N=64 (2 tiles)
__global__ __launch_bounds__(256) void gmfma(const unsigned short* __restrict__ xpad,
                                             const unsigned short* __restrict__ hpad,
                                             const unsigned short* __restrict__ apack,
                                             const unsigned char* __restrict__ done,
                                             float* __restrict__ gates,
                                             int t){
    __shared__ unsigned short panel[3][1536];   // [n 64][stride 24] bf16, k rows 0..15
    int bid = blockIdx.x;
    int b  = bid % 16;
    int r  = bid / 16;
    int nb = r % NB;
    int mh = r / NB;            // 0/1 -> oc base 0/256
    int tid = threadIdx.x;
    int wave = tid >> 6, lane = tid & 63;
    int n0 = nb * 64;
    bool dn = done[t*B_ + b];

    const unsigned short* xb = xpad + ((size_t)(t*B_ + b))*64*640;
    const unsigned short* hb = hpad + (size_t)b*128*640;

    // staging assignment: pass 0..2 -> idx = pass*256+tid over 576 = 9k x 64n
    int sk[3], swaddr[3], soff[3];
    bool svalid[3];
    #pragma unroll
    for (int pass=0; pass<3; ++pass){
        int idx = pass*256 + tid;
        bool v = idx < 576;
        int k = v ? idx/64 : 0;
        int n = idx & 63;
        int p = n0 + n; if (p > 539) p = 539;
        int pbase = (p/20)*22 + (p%20);
        sk[pass] = k;
        soff[pass] = pbase + (k/3)*22 + (k%3);
        swaddr[pass] = n*24 + k;
        svalid[pass] = v;
    }

    // zero the padding k-rows (9..15) of all 3 panels
    for (int q = tid; q < 1344; q += 256){
        int buf = q / 448;
        int rr = q % 448;
        panel[buf][(rr & 63)*24 + 9 + (rr>>6)] = 0;
    }

    // stage chunk 0 directly into panel[0] (x channel 0, no mask)
    #pragma unroll
    for (int pass=0; pass<3; ++pass)
        if (svalid[pass]) panel[0][swaddr[pass]] = xb[soff[pass]];

    // prefetch chunk 1 values into regs
    unsigned short stv[3];
    #pragma unroll
    for (int pass=0; pass<3; ++pass)
        stv[pass] = svalid[pass] ? xb[640 + soff[pass]] : (unsigned short)0;

    // prefetch A for chunk 0
    short8 acur[2], anxt[2];
    #pragma unroll
    for (int i=0;i<2;++i){
        int mt = mh*8 + wave*2 + i;
        acur[i] = *((const short8*)(apack + ((size_t)(0*16 + mt)*64 + lane)*8));
    }

    f32x16 acc[2][2];
    #pragma unroll
    for (int j=0;j<2;++j)
        #pragma unroll
        for (int i=0;i<2;++i)
            #pragma unroll
            for (int rgi=0;rgi<16;++rgi) acc[j][i][rgi] = 0.f;

    __syncthreads();

    for (int c=0; c<192; ++c){
        int cur = c % 3;
        // write staged chunk c+1 into its panel
        if (c+1 < 192){
            int nbuf = (c+1) % 3;
            #pragma unroll
            for (int pass=0; pass<3; ++pass)
                if (svalid[pass]) panel[nbuf][swaddr[pass]] = stv[pass];
        }
        // issue loads for chunk c+2
        if (c+2 < 192){
            int ic = c+2;
            const unsigned short* src;
            bool zero;
            if (ic < 64){ src = xb + ic*640; zero = false; }
            else        { src = hb + (ic-64)*640; zero = dn; }
            #pragma unroll
            for (int pass=0; pass<3; ++pass)
                stv[pass] = (svalid[pass] && !zero) ? src[soff[pass]] : (unsigned short)0;
        }
        // prefetch A for chunk c+1
        if (c+1 < 192){
            #pragma unroll
            for (int i=0;i<2;++i){
                int mt = mh*8 + wave*2 + i;
                anxt[i] = *((const short8*)(apack + ((size_t)((c+1)*16 + mt)*64 + lane)*8));
            }
        }
        __syncthreads();
        // compute chunk c
        #pragma unroll
        for (int j=0;j<2;++j){
            int n = j*32 + (lane & 31);
            short8 bfrag = *((const short8*)(&panel[cur][n*24 + ((lane>>5)<<3)]));
            #pragma unroll
            for (int i=0;i<2;++i)
                acc[j][i] = __builtin_amdgcn_mfma_f32_32x32x16_bf16(acur[i], bfrag, acc[j][i], 0, 0, 0);
        }
        acur[0] = anxt[0]; acur[1] = anxt[1];
    }

    // epilogue: C[row][col], row=(reg&3)+8*(reg>>2)+4*(lane>>5), col=lane&31
    float* gbase = gates + (size_t)b*512*544;
    #pragma unroll
    for (int j=0;j<2;++j){
        int col = n0 + j*32 + (lane & 31);
        if (col >= 544) continue;
        #pragma unroll
        for (int i=0;i<2;++i){
            int ocb = mh*256 + wave*64 + i*32 + 4*(lane>>5);
            #pragma unroll
            for (int rgi=0; rgi<16; ++rgi){
                int row = (rgi & 3) + 8*(rgi>>2);
                gbase[(size_t)(ocb + row)*544 + col] = acc[j][i][rgi];
            }
        }
    }
}

// ---------------- vis LSTM pointwise: bias + gate math; writes vc, vh(f32), hpad(bf16), hre(f32)
__global__ __launch_bounds__(256) void vupdk(const float* __restrict__ gates,
                                             const float* __restrict__ lb,
                                             const unsigned char* __restrict__ done,
                                             float* __restrict__ vh, float* __restrict__ vc,
                                             unsigned short* __restrict__ hpad,
                                             float* __restrict__ hre, int t){
    int idx = blockIdx.x*256 + threadIdx.x;   // 16*128*540
    int p = idx % 540;
    int c = (idx/540) & 127;
    int b = idx / (540*128);
    const float* gb = gates + (size_t)b*512*544;
    float gi = gb[(size_t)(      c)*544 + p] + lb[      c];
    float gf = gb[(size_t)(128 + c)*544 + p] + lb[128 + c];
    float go = gb[(size_t)(256 + c)*544 + p] + lb[256 + c];
    float gg = gb[(size_t)(384 + c)*544 + p] + lb[384 + c];
    float m  = done[t*B_ + b] ? 0.f : 1.f;
    float cold = vc[idx] * m;
    float cn = sigm(gf)*cold + sigm(gi)*tanhf(gg);
    float hn = sigm(go)*tanhf(cn);
    vc[idx] = cn;
    vh[idx] = hn;
    hpad[((size_t)b*128 + c)*640 + (p/20+1)*22 + (p%20) + 1] = f2bf(hn);
    int flat = c*540 + p;
    hre[((size_t)b*540 + (flat/2560)*20 + (flat/128)%20)*128 + (flat & 127)] = hn;
}

// ---------------- fused core step: qMLP + attention + answerMLP + LSTM. one block per b
__global__ __launch_bounds__(512) void corek(const float* __restrict__ hprev,
                                             const float* __restrict__ hre,
                                             const float* __restrict__ S,
                                             const float* __restrict__ qw1, const float* __restrict__ qb1,
                                             const float* __restrict__ qw2, const float* __restrict__ qb2,
                                             const float* __restrict__ qw3, const float* __restrict__ qb3,
                                             const float* __restrict__ aw1, const float* __restrict__ ab1,
                                             const float* __restrict__ aw2, const float* __restrict__ ab2,
                                             const float* __restrict__ wihT, const float* __restrict__ whhT,
                                             const float* __restrict__ bih, const float* __restrict__ bhh,
                                             const float* __restrict__ reward, const int* __restrict__ lact,
                                             const unsigned char* __restrict__ done,
                                             float* __restrict__ ccb, float* __restrict__ outs, int t){
    __shared__ float hs[256], q1[128], q2[288], q3[288];
    __shared__ float elog[4][P_];
    __shared__ float red[32];
    __shared__ float ansv[1056];
    __shared__ float hid[512];
    __shared__ float cis[256], hs2[256];
    __shared__ float gb[1024];
    int b = blockIdx.x, tid = threadIdx.x;
    if (tid < 256) hs[tid] = hprev[b*256+tid];
    __syncthreads();
    if (tid < 128){
        float a = qb1[tid];
        for (int i=0;i<256;++i) a += hs[i]*qw1[i*128+tid];
        q1[tid] = fmaxf(a,0.f);
    }
    __syncthreads();
    if (tid < 288){
        float a = qb2[tid];
        for (int i=0;i<128;++i) a += q1[i]*qw2[i*288+tid];
        q2[tid] = fmaxf(a,0.f);
    }
    __syncthreads();
    if (tid < 288){
        float a = qb3[tid];
        for (int i=0;i<288;++i) a += q2[i]*qw3[i*288+tid];
        q3[tid] = a;
        ansv[736+tid] = a;
    }
    if (tid == 0){ float r = reward[t*B_+b]; ansv[1024] = fminf(1.f,fmaxf(-1.f,r)); }
    if (tid >= 32 && tid < 32+NA) ansv[1025 + tid-32] = (lact[t*B_+b] == tid-32) ? 1.f : 0.f;
    __syncthreads();
    const float* hrb = hre + (size_t)b*P_*128;
    for (int idx = tid; idx < 4*P_; idx += 512){
        int qi = idx / P_, p = idx % P_;
        const float* hp = hrb + (size_t)p*128;
        const float* qv = q3 + qi*72;
        float4 h0 = *((const float4*)hp);
        float4 h1 = *((const float4*)(hp+4));
        float a = h0.x*qv[0]+h0.y*qv[1]+h0.z*qv[2]+h0.w*qv[3]
                + h1.x*qv[4]+h1.y*qv[5]+h1.z*qv[6]+h1.w*qv[7];
        const float* Sp = S + p*64;
        #pragma unroll
        for (int s2=0;s2<16;++s2){
            float4 sv = *((const float4*)(Sp + 4*s2));
            a += sv.x*qv[8+4*s2] + sv.y*qv[9+4*s2] + sv.z*qv[10+4*s2] + sv.w*qv[11+4*s2];
        }
        elog[qi][p] = a;
    }
    __syncthreads();
    {
        int qi = tid >> 7, lt = tid & 127;
        float mx = -1e30f;
        for (int p = lt; p < P_; p += 128) mx = fmaxf(mx, elog[qi][p]);
        for (int off=32; off; off>>=1) mx = fmaxf(mx, __shfl_down(mx, off));
        if ((tid & 63) == 0) red[tid>>6] = mx;
        __syncthreads();
        if (tid < 4) red[16+tid] = fmaxf(red[2*tid], red[2*tid+1]);
        __syncthreads();
        mx = red[16+qi];
        float s = 0.f;
        for (int p = lt; p < P_; p += 128){ float e = expf(elog[qi][p]-mx); elog[qi][p] = e; s += e; }
        for (int off=32; off; off>>=1) s += __shfl_down(s, off);
        if ((tid & 63) == 0) red[8 + (tid>>6)] = s;
        __syncthreads();
        if (tid < 4) red[24+tid] = red[8+2*tid] + red[8+2*tid+1];
        __syncthreads();
    }
    for (int idx = tid; idx < 736; idx += 512){
        int qi = idx / 184, v = idx % 184;
        float a = 0.f;
        if (v < 120){
            const float* basep = hrb + 8 + v;
            for (int p=0;p<P_;++p) a += elog[qi][p]*basep[(size_t)p*128];
        } else {
            const float* basep = S + (v-120);
            for (int p=0;p<P_;++p) a += elog[qi][p]*basep[p*64];
        }
        ansv[qi*184+v] = a / red[24+qi];
    }
    __syncthreads();
    {
        float a = ab1[tid];
        for (int i=0;i<1043;++i) a += ansv[i]*aw1[(size_t)i*512+tid];
        hid[tid] = fmaxf(a, 0.f);
    }
    float m = done[t*B_+b] ? 0.f : 1.f;
    if (tid < 256) hs2[tid] = hs[tid]*m;
    __syncthreads();
    if (tid < 256){
        float o = ab2[tid];
        for (int j=0;j<512;++j) o += hid[j]*aw2[j*256+tid];
        cis[tid] = o;
    }
    __syncthreads();
    for (int g = tid; g < 1024; g += 512){
        float a = bih[g] + bhh[g];
        for (int j=0;j<256;++j) a += cis[j]*wihT[j*1024+g] + hs2[j]*whhT[j*1024+g];
        gb[g] = a;
    }
    __syncthreads();
    if (tid < 256){
        float gi = gb[tid], gf = gb[256+tid], gg = gb[512+tid], go = gb[768+tid];
        float cold = ccb[b*256+tid]*m;
        float cn = sigm(gf)*cold + sigm(gi)*tanhf(gg);
        float hn = sigm(go)*tanhf(cn);
        ccb[b*256+tid] = cn;
        outs[(t*B_+b)*256+tid] = hn;
    }
}

// ---------------- heads
__global__ __launch_bounds__(64) void finalk(const float* __restrict__ outs,
                                             const float* __restrict__ pw, const float* __restrict__ pb,
                                             const float* __restrict__ vw, const float* __restrict__ vb,
                                             float* __restrict__ dout){
    int row = blockIdx.x, tid = threadIdx.x;
    __shared__ float os[256];
    __shared__ float lg[NA];
    for (int i=tid; i<256; i+=64) os[i] = outs[row*256+i];
    __syncthreads();
    if (tid < NA){
        float a = pb[tid];
        for (int i=0;i<256;++i) a += os[i]*pw[i*NA+tid];
        lg[tid] = a;
        dout[row*NA + tid] = a;
    } else if (tid == 32){
        float a = vb[0];
        for (int i=0;i<256;++i) a += os[i]*vw[i];
        dout[9216 + row] = a;
    }
    __syncthreads();
    if (tid == 0){
        int am = 0; float bv = lg[0];
        for (int j=1;j<NA;++j) if (lg[j] > bv){ bv = lg[j]; am = j; }
        dout[9728 + row] = (float)am;
    }
}

extern "C" void kernel_launch(void* const* d_in, const int* in_sizes, int n_in,
                              void* d_out, int out_size, void* d_ws, size_t ws_size,
                              hipStream_t stream) {
    const float* frame   = (const float*)d_in[0];
    const unsigned char* done = (const unsigned char*)d_in[1];
    const int*   lact    = (const int*)d_in[2];
    const float* reward  = (const float*)d_in[3];
    const float* core_h0 = (const float*)d_in[4];
    const float* core_c0 = (const float*)d_in[5];
    const float* conv_h0 = (const float*)d_in[6];
    const float* conv_c0 = (const float*)d_in[7];
    const float* cnn_w1  = (const float*)d_in[8];
    const float* cnn_b1  = (const float*)d_in[9];
    const float* cnn_w2  = (const float*)d_in[10];
    const float* cnn_b2  = (const float*)d_in[11];
    const float* lstm_w  = (const float*)d_in[12];
    const float* lstm_b  = (const float*)d_in[13];
    const float* qw1 = (const float*)d_in[14]; const float* qb1 = (const float*)d_in[15];
    const float* qw2 = (const float*)d_in[16]; const float* qb2 = (const float*)d_in[17];
    const float* qw3 = (const float*)d_in[18]; const float* qb3 = (const float*)d_in[19];
    const float* aw1 = (const float*)d_in[20]; const float* ab1 = (const float*)d_in[21];
    const float* aw2 = (const float*)d_in[22]; const float* ab2 = (const float*)d_in[23];
    const float* w_ih = (const float*)d_in[24]; const float* w_hh = (const float*)d_in[25];
    const float* b_ih = (const float*)d_in[26]; const float* b_hh = (const float*)d_in[27];
    const float* pw = (const float*)d_in[28]; const float* pb = (const float*)d_in[29];
    const float* vw = (const float*)d_in[30]; const float* vb = (const float*)d_in[31];

    float* ws = (float*)d_ws;
    float* dout = (float*)d_out;

    // ws layout (float offsets):
    // [0 .. 10,485,760)                xpad bf16 (20,971,520 u16)
    // [10,485,760 .. 44,564,480)       c1 fp32 (transient, consumed by conv2k)
    //   -- the following live INSIDE the c1 range, initialized only after conv2k:
    unsigned short* xpad  = (unsigned short*)ws;                       // 41.9 MB
    float* c1    = ws + 10485760;
    unsigned short* hpad  = (unsigned short*)(ws + 10485760);          // 1,310,720 u16
    unsigned short* apack = (unsigned short*)(ws + 11141120);          // 1,572,864 u16
    float* gates = ws + 11927552;      // 16*512*544 = 4,456,448
    float* vh    = ws + 16384000;      // 1,105,920
    float* vc    = ws + 17489920;      // 1,105,920
    float* hre   = ws + 18595840;      // 1,105,920
    float* S     = ws + 19701760;      // 34,560
    float* wihT  = ws + 19736320;      // 262,144
    float* whhT  = ws + 19998464;      // 262,144
    float* outs  = ws + 20260608;      // 131,072
    float* ccb   = ws + 20391680;      // 4,096

    // zero xpad (borders must be 0; interiors overwritten by conv2k). Does not overlap c1.
    hipMemsetAsync(xpad, 0, (size_t)20971520*2, stream);

    // CNN
    conv1k<<<512*52, 256, 0, stream>>>(frame, cnn_w1, cnn_b1, c1);
    conv2k<<<512*27, 256, 0, stream>>>(c1, cnn_w2, cnn_b2, xpad);

    // everything below lives in the (now dead) c1 region — runs after conv2k in stream order
    hipMemsetAsync(hpad, 0, (size_t)1310720*2, stream);
    sbasisk<<<135, 256, 0, stream>>>(S);
    apackk<<<6144, 256, 0, stream>>>(lstm_w, apack);
    transk<<<1024, 256, 0, stream>>>(w_ih, wihT, 1024, 256);
    transk<<<1024, 256, 0, stream>>>(w_hh, whhT, 1024, 256);
    h0packk<<<4320, 256, 0, stream>>>(conv_h0, hpad);
    hipMemcpyAsync(vh,  conv_h0, (size_t)16*128*540*sizeof(float), hipMemcpyDeviceToDevice, stream);
    hipMemcpyAsync(vc,  conv_c0, (size_t)16*128*540*sizeof(float), hipMemcpyDeviceToDevice, stream);
    hipMemcpyAsync(ccb, core_c0, (size_t)16*256*sizeof(float),     hipMemcpyDeviceToDevice, stream);

    for (int t = 0; t < T_; ++t){
        gmfma<<<288, 256, 0, stream>>>(xpad, hpad, apack, done, gates, t);
        vupdk<<<4320, 256, 0, stream>>>(gates, lstm_b, done, vh, vc, hpad, hre, t);
        const float* hprev = (t == 0) ? core_h0 : (outs + (size_t)(t-1)*B_*256);
        corek<<<16, 512, 0, stream>>>(hprev, hre, S, qw1,qb1,qw2,qb2,qw3,qb3,
                                      aw1,ab1,aw2,ab2, wihT,whhT,b_ih,b_hh,
                                      reward, lact, done, ccb, outs, t);
    }

    finalk<<<512, 64, 0, stream>>>(outs, pw, pb, vw, vb, dout);

    hipMemcpyAsync(dout + 10240,   outs + (size_t)31*B_*256, (size_t)16*256*sizeof(float), hipMemcpyDeviceToDevice, stream);
    hipMemcpyAsync(dout + 14336,   ccb, (size_t)16*256*sizeof(float), hipMemcpyDeviceToDevice, stream);
    hipMemcpyAsync(dout + 18432,   vh,  (size_t)16*128*540*sizeof(float), hipMemcpyDeviceToDevice, stream);
    hipMemcpyAsync(dout + 1124352, vc,  (size_t)16*128*540*sizeof(float), hipMemcpyDeviceToDevice, stream);
}

// Round 4
// 9460.208 us; speedup vs baseline: 3.4652x; 1.1043x over previous
//
#include <hip/hip_runtime.h>
#include <math.h>

#define T_ 32
#define B_ 16
#define NA 18
#define P_ 540   // 27*20

typedef __attribute__((ext_vector_type(8)))  short short8;
typedef __attribute__((ext_vector_type(16))) float f32x16;

__device__ __forceinline__ float sigm(float x){ return 1.0f/(1.0f+expf(-x)); }
__device__ __forceinline__ unsigned short f2bf(float f){
    unsigned u = __float_as_uint(f);
    u += 0x7fff + ((u>>16)&1u);
    return (unsigned short)(u>>16);
}
__device__ __forceinline__ float bfu(unsigned short u){ return __uint_as_float(((unsigned)u)<<16); }

// ---------------- conv1: (512,3,210,160) -> c1pad bf16 [512][32][56][42], k8 s4 padH(1,1) W(2,2)
__global__ __launch_bounds__(256) void conv1k(const float* __restrict__ frame,
                                              const float* __restrict__ w,
                                              const float* __restrict__ bias,
                                              unsigned short* __restrict__ c1pad){
    __shared__ float tile[4032];  // 3ch * 8rows * 168cols (padded)
    int bid = blockIdx.x;
    int n = bid / 52, oh = bid % 52;
    int tid = threadIdx.x;
    const float* fb = frame + (size_t)n*3*210*160;
    for (int s = tid; s < 4032; s += 256){
        int col = s % 168;
        int row = (s/168) & 7;
        int ic  = s / 1344;
        int iy = oh*4 - 1 + row;
        int ix = col - 2;
        float v = 0.f;
        if (iy >= 0 && iy < 210 && ix >= 0 && ix < 160) v = fb[ic*33600 + iy*160 + ix];
        tile[s] = v;
    }
    __syncthreads();
    int oc = tid & 31, grp = tid >> 5;      // grp 0..7 -> ow = grp*5..grp*5+4
    float acc[5] = {0.f,0.f,0.f,0.f,0.f};
    const float* wb = w + oc*192;
    for (int ic=0; ic<3; ++ic){
        #pragma unroll
        for (int kh=0; kh<8; ++kh){
            const float* wr = wb + ic*64 + kh*8;
            float4 w0 = *((const float4*)wr);
            float4 w1 = *((const float4*)(wr+4));
            const float* row = tile + ic*1344 + kh*168 + grp*20;
            float r[24];
            *((float4*)(r+ 0)) = *((const float4*)(row+ 0));
            *((float4*)(r+ 4)) = *((const float4*)(row+ 4));
            *((float4*)(r+ 8)) = *((const float4*)(row+ 8));
            *((float4*)(r+12)) = *((const float4*)(row+12));
            *((float4*)(r+16)) = *((const float4*)(row+16));
            *((float4*)(r+20)) = *((const float4*)(row+20));
            #pragma unroll
            for (int o=0;o<5;++o){
                acc[o] += r[o*4+0]*w0.x + r[o*4+1]*w0.y + r[o*4+2]*w0.z + r[o*4+3]*w0.w
                        + r[o*4+4]*w1.x + r[o*4+5]*w1.y + r[o*4+6]*w1.z + r[o*4+7]*w1.w;
            }
        }
    }
    float bi = bias[oc];
    unsigned short* ob = c1pad + ((size_t)(n*32 + oc)*56 + oh+2)*42 + 1;
    #pragma unroll
    for (int o=0;o<5;++o) ob[grp*5+o] = f2bf(acc[o] + bi);
}

// ---------------- conv2 A-pack: cnn_w2 (64,32,4,4) -> apack2[32 ic][2 mt][64 lane][8] bf16
__global__ void apack2k(const float* __restrict__ w2, unsigned short* __restrict__ ap){
    int idx = blockIdx.x*256 + threadIdx.x;
    if (idx >= 32768) return;
    int j = idx & 7;
    int lane = (idx>>3) & 63;
    int mt = (idx>>9) & 1;
    int ic = idx >> 10;
    int k = ((lane>>5)<<3) + j;          // kh*4+kw
    int oc = mt*32 + (lane & 31);
    ap[idx] = f2bf(w2[((oc*32 + ic)<<4) + k]);
}

// ---------------- conv2 MFMA: c1pad bf16 -> xpad bf16 [512][64][640], k4 s2 padH(2,2) W(1,1)
// grid 2560 = 512 s * 5 nb(128 cols); 256 thr = 4 waves; wave = (mt=w>>1, nt base=(w&1)*2)
__global__ __launch_bounds__(256) void c2mfma(const unsigned short* __restrict__ c1pad,
                                              const unsigned short* __restrict__ apack2,
                                              const float* __restrict__ bias,
                                              unsigned short* __restrict__ xpad){
    __shared__ unsigned short p2[2][3072];   // [n 128][stride 24]
    __shared__ float bsm[64];
    int bid = blockIdx.x;
    int s = bid / 5;
    int n0 = (bid % 5) * 128;
    int tid = threadIdx.x;
    int wave = tid >> 6, lane = tid & 63;
    int khalf = (lane>>5) << 3;
    if (tid < 64) bsm[tid] = bias[tid];
    const unsigned short* cb = c1pad + (size_t)s*32*2352;

    int soff[8], swaddr[8];
    #pragma unroll
    for (int q=0;q<8;++q){
        int idx = q*256 + tid;
        int n = idx & 127, k = idx >> 7;
        int p = n0 + n; if (p > 539) p = 539;
        soff[q] = ((p/20)*2 + (k>>2))*42 + (p%20)*2 + (k&3);
        swaddr[q] = n*24 + k;
    }
    #pragma unroll
    for (int q=0;q<8;++q) p2[0][swaddr[q]] = cb[soff[q]];
    unsigned short rv[8];
    #pragma unroll
    for (int q=0;q<8;++q) rv[q] = cb[2352 + soff[q]];

    int mt = wave >> 1, ntb = (wave & 1) * 2;
    short8 acur = *((const short8*)(apack2 + ((size_t)mt*64 + lane)*8));
    short8 anxt;
    f32x16 acc[2];
    #pragma unroll
    for (int jj=0;jj<2;++jj)
        #pragma unroll
        for (int rg=0;rg<16;++rg) acc[jj][rg] = 0.f;
    __syncthreads();

    for (int c=0; c<32; ++c){
        int buf = c & 1;
        if (c < 31){
            #pragma unroll
            for (int q=0;q<8;++q) p2[buf^1][swaddr[q]] = rv[q];
        }
        if (c < 30){
            const unsigned short* src = cb + (size_t)(c+2)*2352;
            #pragma unroll
            for (int q=0;q<8;++q) rv[q] = src[soff[q]];
        }
        if (c < 31) anxt = *((const short8*)(apack2 + ((size_t)((c+1)*2 + mt)*64 + lane)*8));
        #pragma unroll
        for (int jj=0;jj<2;++jj){
            int n = (ntb+jj)*32 + (lane & 31);
            short8 bf = *((const short8*)(&p2[buf][n*24 + khalf]));
            acc[jj] = __builtin_amdgcn_mfma_f32_32x32x16_bf16(acur, bf, acc[jj], 0, 0, 0);
        }
        acur = anxt;
        __syncthreads();
    }
    #pragma unroll
    for (int jj=0;jj<2;++jj){
        int pos = n0 + (ntb+jj)*32 + (lane & 31);
        if (pos >= 540) continue;
        int y = pos/20, x = pos%20;
        unsigned short* op = xpad + (size_t)s*64*640 + (y+1)*22 + x + 1;
        #pragma unroll
        for (int rg=0; rg<16; ++rg){
            int oc = mt*32 + (rg & 3) + 8*(rg>>2) + 4*(lane>>5);
            op[(size_t)oc*640] = f2bf(acc[jj][rg] + bsm[oc]);
        }
    }
}

// ---------------- spatial basis S[540][64]
__global__ void sbasisk(float* __restrict__ S){
    int idx = blockIdx.x*256 + threadIdx.x;
    if (idx >= P_*64) return;
    int s = idx & 63, p = idx >> 6;
    int y = p/20, x = p%20;
    int u = s >> 3, v = s & 7;
    double a  = cos((double)((y+1)*(u+1)) * M_PI / 27.0);
    double bb = cos((double)((x+1)*(v+1)) * M_PI / 20.0);
    S[idx] = (float)(a*bb);
}

// ---------------- generic transpose (R,C) -> out[c*R+r]
__global__ void transk(const float* __restrict__ in, float* __restrict__ out, int R, int C){
    int idx = blockIdx.x*256 + threadIdx.x;
    if (idx >= R*C) return;
    int r = idx / C, c = idx % C;
    out[(size_t)c*R + r] = in[idx];
}

// ---------------- gates A-pack: lstm_w (512,192,3,3) -> apack[192][16][64][8] bf16 (k>=9 -> 0)
__global__ void apackk(const float* __restrict__ lw, unsigned short* __restrict__ ap){
    int idx = blockIdx.x*256 + threadIdx.x;
    if (idx >= 1572864) return;
    int j = idx & 7;
    int lane = (idx>>3) & 63;
    int mt = (idx>>9) & 15;
    int ch = idx >> 13;
    int kk = ((lane>>5)<<3) + j;
    int oc = mt*32 + (lane & 31);
    ap[idx] = (kk < 9) ? f2bf(lw[(size_t)oc*1728 + ch*9 + kk]) : (unsigned short)0;
}

// ---------------- pack conv_h0 fp32 -> hpad bf16 interior
__global__ void h0packk(const float* __restrict__ h0, unsigned short* __restrict__ hpad){
    int idx = blockIdx.x*256 + threadIdx.x;
    if (idx >= 16*128*540) return;
    int plane = idx / 540, p = idx % 540;
    hpad[(size_t)plane*640 + (p/20+1)*22 + (p%20) + 1] = f2bf(h0[idx]);
}

// ---------------- gates GEMM (bf16 MFMA 32x32x16), 4 chunks per barrier
// grid 288 = 16b * 9nb * 2mh ; 256 threads = 4 waves; wave: M=64(2 mt) x N=64(2 nt)
__global__ __launch_bounds__(256) void gmfma(const unsigned short* __restrict__ xpad,
                                             const unsigned short* __restrict__ hpad,
                                             const unsigned short* __restrict__ apack,
                                             const unsigned char* __restrict__ done,
                                             float* __restrict__ gates,
                                             int t){
    __shared__ unsigned short panel[2][6144];   // 4 chunks x [n 64][stride 24]
    int bid = blockIdx.x;
    int b  = bid % 16;
    int r  = bid / 16;
    int nb = r % 9;
    int mh = r / 9;
    int tid = threadIdx.x;
    int wave = tid >> 6, lane = tid & 63;
    int khalf = (lane>>5) << 3;
    int n0 = nb * 64;
    bool dn = done[t*B_ + b];

    const unsigned short* xb = xpad + ((size_t)(t*B_ + b))*64*640;
    const unsigned short* hb = hpad + (size_t)b*128*640;

    int soff[9], swaddr[9], gq[9];
    #pragma unroll
    for (int q=0;q<9;++q){
        int idx = q*256 + tid;
        int g = idx / 576;
        int rr = idx % 576;
        int k = rr / 64, n = rr & 63;
        int p = n0 + n; if (p > 539) p = 539;
        int pbase = (p/20)*22 + (p%20);
        soff[q] = pbase + (k/3)*22 + (k%3);
        swaddr[q] = g*1536 + n*24 + k;
        gq[q] = g;
    }
    // zero padding k-rows 9..15 of both buffers
    for (int s2 = tid; s2 < 3584; s2 += 256){
        int bf2 = s2 / 1792, r2 = s2 % 1792;
        int g2 = r2 / 448, rr2 = r2 % 448;
        panel[bf2][g2*1536 + (rr2 & 63)*24 + 9 + (rr2>>6)] = 0;
    }
    // stage group 0 (channels 0..3, x)
    #pragma unroll
    for (int q=0;q<9;++q) panel[0][swaddr[q]] = xb[gq[q]*640 + soff[q]];
    // load group 1 (channels 4..7, x)
    unsigned short rv[9];
    #pragma unroll
    for (int q=0;q<9;++q) rv[q] = xb[(4+gq[q])*640 + soff[q]];

    short8 acur[4][2], anxt[4][2];
    #pragma unroll
    for (int g=0;g<4;++g)
        #pragma unroll
        for (int i=0;i<2;++i){
            int mt = mh*8 + wave*2 + i;
            acur[g][i] = *((const short8*)(apack + ((size_t)(g*16 + mt)*64 + lane)*8));
        }

    f32x16 acc[2][2];
    #pragma unroll
    for (int j=0;j<2;++j)
        #pragma unroll
        for (int i=0;i<2;++i)
            #pragma unroll
            for (int rg=0;rg<16;++rg) acc[j][i][rg] = 0.f;

    __syncthreads();

    for (int it=0; it<48; ++it){
        int buf = it & 1;
        if (it < 47){
            #pragma unroll
            for (int q=0;q<9;++q) panel[buf^1][swaddr[q]] = rv[q];
        }
        if (it < 46){
            int icb = (it+2)*4;
            #pragma unroll
            for (int q=0;q<9;++q){
                int ic = icb + gq[q];
                rv[q] = (ic < 64) ? xb[ic*640 + soff[q]]
                                  : (dn ? (unsigned short)0 : hb[(ic-64)*640 + soff[q]]);
            }
        }
        if (it < 47){
            int cb2 = (it+1)*4;
            #pragma unroll
            for (int g=0;g<4;++g)
                #pragma unroll
                for (int i=0;i<2;++i){
                    int mt = mh*8 + wave*2 + i;
                    anxt[g][i] = *((const short8*)(apack + ((size_t)((cb2+g)*16 + mt)*64 + lane)*8));
                }
        }
        #pragma unroll
        for (int g=0;g<4;++g){
            #pragma unroll
            for (int j=0;j<2;++j){
                int n = j*32 + (lane & 31);
                short8 bf = *((const short8*)(&panel[buf][g*1536 + n*24 + khalf]));
                #pragma unroll
                for (int i=0;i<2;++i)
                    acc[j][i] = __builtin_amdgcn_mfma_f32_32x32x16_bf16(acur[g][i], bf, acc[j][i], 0, 0, 0);
            }
        }
        #pragma unroll
        for (int g=0;g<4;++g){ acur[g][0] = anxt[g][0]; acur[g][1] = anxt[g][1]; }
        __syncthreads();
    }

    // epilogue: row=(reg&3)+8*(reg>>2)+4*(lane>>5), col=lane&31
    float* gbase = gates + (size_t)b*512*544;
    #pragma unroll
    for (int j=0;j<2;++j){
        int col = n0 + j*32 + (lane & 31);
        if (col >= 544) continue;
        #pragma unroll
        for (int i=0;i<2;++i){
            int ocb = mh*256 + wave*64 + i*32 + 4*(lane>>5);
            #pragma unroll
            for (int rg=0; rg<16; ++rg){
                int row = (rg & 3) + 8*(rg>>2);
                gbase[(size_t)(ocb + row)*544 + col] = acc[j][i][rg];
            }
        }
    }
}

// ---------------- vis LSTM pointwise: writes vc, vh(f32), hpad(bf16), hre_all[t] (bf16)
__global__ __launch_bounds__(256) void vupdk(const float* __restrict__ gates,
                                             const float* __restrict__ lb,
                                             const unsigned char* __restrict__ done,
                                             float* __restrict__ vh, float* __restrict__ vc,
                                             unsigned short* __restrict__ hpad,
                                             unsigned short* __restrict__ hreA, int t){
    int idx = blockIdx.x*256 + threadIdx.x;   // 16*128*540
    int p = idx % 540;
    int c = (idx/540) & 127;
    int b = idx / (540*128);
    const float* gb = gates + (size_t)b*512*544;
    float gi = gb[(size_t)(      c)*544 + p] + lb[      c];
    float gf = gb[(size_t)(128 + c)*544 + p] + lb[128 + c];
    float go = gb[(size_t)(256 + c)*544 + p] + lb[256 + c];
    float gg = gb[(size_t)(384 + c)*544 + p] + lb[384 + c];
    float m  = done[t*B_ + b] ? 0.f : 1.f;
    float cold = vc[idx] * m;
    float cn = sigm(gf)*cold + sigm(gi)*tanhf(gg);
    float hn = sigm(go)*tanhf(cn);
    vc[idx] = cn;
    vh[idx] = hn;
    hpad[((size_t)b*128 + c)*640 + (p/20+1)*22 + (p%20) + 1] = f2bf(hn);
    int flat = c*540 + p;
    int pos = (flat/2560)*20 + (flat/128)%20;
    int ch  = flat & 127;
    hreA[((size_t)(t*B_ + b)*540 + pos)*128 + ch] = f2bf(hn);
}

// ---------------- core: full T loop in ONE dispatch. one block per b, 512 threads.
__global__ __launch_bounds__(512) void corek2(const unsigned short* __restrict__ hreA,
                                              const float* __restrict__ S,
                                              const float* __restrict__ qw1, const float* __restrict__ qb1,
                                              const float* __restrict__ qw2, const float* __restrict__ qb2,
                                              const float* __restrict__ qw3, const float* __restrict__ qb3,
                                              const float* __restrict__ aw1, const float* __restrict__ ab1,
                                              const float* __restrict__ aw2, const float* __restrict__ ab2,
                                              const float* __restrict__ wihT, const float* __restrict__ whhT,
                                              const float* __restrict__ bih, const float* __restrict__ bhh,
                                              const float* __restrict__ reward, const int* __restrict__ lact,
                                              const unsigned char* __restrict__ done,
                                              const float* __restrict__ core_h0, const float* __restrict__ core_c0,
                                              float* __restrict__ ccb, float* __restrict__ outs){
    __shared__ float hs[256], cs[256], hs2[256], q1[128], q2[288], q3[288];
    __shared__ float elog[4][P_];
    __shared__ float red[32];
    __shared__ float ansv[1056];
    __shared__ float hid[512];
    __shared__ float cis[256];
    __shared__ float gb[1024];
    int b = blockIdx.x, tid = threadIdx.x;
    if (tid < 256){ hs[tid] = core_h0[b*256+tid]; cs[tid] = core_c0[b*256+tid]; }
    __syncthreads();

    for (int t = 0; t < T_; ++t){
        if (tid < 128){
            float a = qb1[tid];
            for (int i=0;i<256;++i) a += hs[i]*qw1[i*128+tid];
            q1[tid] = fmaxf(a,0.f);
        }
        __syncthreads();
        if (tid < 288){
            float a = qb2[tid];
            for (int i=0;i<128;++i) a += q1[i]*qw2[i*288+tid];
            q2[tid] = fmaxf(a,0.f);
        }
        __syncthreads();
        if (tid < 288){
            float a = qb3[tid];
            for (int i=0;i<288;++i) a += q2[i]*qw3[i*288+tid];
            q3[tid] = a;
            ansv[736+tid] = a;
        }
        if (tid == 0){ float r = reward[t*B_+b]; ansv[1024] = fminf(1.f,fmaxf(-1.f,r)); }
        if (tid >= 32 && tid < 32+NA) ansv[1025 + tid-32] = (lact[t*B_+b] == tid-32) ? 1.f : 0.f;
        __syncthreads();

        const unsigned short* hrb = hreA + (size_t)(t*B_ + b)*540*128;
        for (int idx = tid; idx < 4*P_; idx += 512){
            int qi = idx / P_, p = idx % P_;
            const unsigned short* hp = hrb + (size_t)p*128;
            uint4 hv = *((const uint4*)hp);
            const float* qv = q3 + qi*72;
            float a = __uint_as_float(hv.x<<16)*qv[0] + __uint_as_float(hv.x & 0xffff0000u)*qv[1]
                    + __uint_as_float(hv.y<<16)*qv[2] + __uint_as_float(hv.y & 0xffff0000u)*qv[3]
                    + __uint_as_float(hv.z<<16)*qv[4] + __uint_as_float(hv.z & 0xffff0000u)*qv[5]
                    + __uint_as_float(hv.w<<16)*qv[6] + __uint_as_float(hv.w & 0xffff0000u)*qv[7];
            const float* Sp = S + p*64;
            #pragma unroll
            for (int s2=0;s2<16;++s2){
                float4 sv = *((const float4*)(Sp + 4*s2));
                a += sv.x*qv[8+4*s2] + sv.y*qv[9+4*s2] + sv.z*qv[10+4*s2] + sv.w*qv[11+4*s2];
            }
            elog[qi][p] = a;
        }
        __syncthreads();
        {
            int qi = tid >> 7, lt = tid & 127;
            float mx = -1e30f;
            for (int p = lt; p < P_; p += 128) mx = fmaxf(mx, elog[qi][p]);
            for (int off=32; off; off>>=1) mx = fmaxf(mx, __shfl_down(mx, off));
            if ((tid & 63) == 0) red[tid>>6] = mx;
            __syncthreads();
            if (tid < 4) red[16+tid] = fmaxf(red[2*tid], red[2*tid+1]);
            __syncthreads();
            mx = red[16+qi];
            float sm = 0.f;
            for (int p = lt; p < P_; p += 128){ float e = expf(elog[qi][p]-mx); elog[qi][p] = e; sm += e; }
            for (int off=32; off; off>>=1) sm += __shfl_down(sm, off);
            if ((tid & 63) == 0) red[8 + (tid>>6)] = sm;
            __syncthreads();
            if (tid < 4) red[24+tid] = red[8+2*tid] + red[8+2*tid+1];
            __syncthreads();
        }
        for (int idx = tid; idx < 736; idx += 512){
            int qi = idx / 184, v = idx % 184;
            float a = 0.f;
            if (v < 120){
                const unsigned short* basep = hrb + 8 + v;
                for (int p=0;p<P_;++p) a += elog[qi][p]*bfu(basep[(size_t)p*128]);
            } else {
                const float* basep = S + (v-120);
                for (int p=0;p<P_;++p) a += elog[qi][p]*basep[p*64];
            }
            ansv[qi*184+v] = a / red[24+qi];
        }
        __syncthreads();
        {
            float a = ab1[tid];
            for (int i=0;i<1043;++i) a += ansv[i]*aw1[(size_t)i*512+tid];
            hid[tid] = fmaxf(a, 0.f);
        }
        float m = done[t*B_+b] ? 0.f : 1.f;
        if (tid < 256) hs2[tid] = hs[tid]*m;
        __syncthreads();
        if (tid < 256){
            float o = ab2[tid];
            for (int j=0;j<512;++j) o += hid[j]*aw2[j*256+tid];
            cis[tid] = o;
        }
        __syncthreads();
        for (int g = tid; g < 1024; g += 512){
            float a = bih[g] + bhh[g];
            for (int j=0;j<256;++j) a += cis[j]*wihT[j*1024+g] + hs2[j]*whhT[j*1024+g];
            gb[g] = a;
        }
        __syncthreads();
        if (tid < 256){
            float gi = gb[tid], gf = gb[256+tid], gg = gb[512+tid], go = gb[768+tid];
            float cold = cs[tid]*m;
            float cn = sigm(gf)*cold + sigm(gi)*tanhf(gg);
            float hn = sigm(go)*tanhf(cn);
            cs[tid] = cn;
            hs[tid] = hn;
            outs[(t*B_+b)*256+tid] = hn;
        }
        __syncthreads();
    }
    if (tid < 256) ccb[b*256+tid] = cs[tid];
}

// ---------------- heads
__global__ __launch_bounds__(64) void finalk(const float* __restrict__ outs,
                                             const float* __restrict__ pw, const float* __restrict__ pb,
                                             const float* __restrict__ vw, const float* __restrict__ vb,
                                             float* __restrict__ dout){
    int row = blockIdx.x, tid = threadIdx.x;
    __shared__ float os[256];
    __shared__ float lg[NA];
    for (int i=tid; i<256; i+=64) os[i] = outs[row*256+i];
    __syncthreads();
    if (tid < NA){
        float a = pb[tid];
        for (int i=0;i<256;++i) a += os[i]*pw[i*NA+tid];
        lg[tid] = a;
        dout[row*NA + tid] = a;
    } else if (tid == 32){
        float a = vb[0];
        for (int i=0;i<256;++i) a += os[i]*vw[i];
        dout[9216 + row] = a;
    }
    __syncthreads();
    if (tid == 0){
        int am = 0; float bv = lg[0];
        for (int j=1;j<NA;++j) if (lg[j] > bv){ bv = lg[j]; am = j; }
        dout[9728 + row] = (float)am;
    }
}

extern "C" void kernel_launch(void* const* d_in, const int* in_sizes, int n_in,
                              void* d_out, int out_size, void* d_ws, size_t ws_size,
                              hipStream_t stream) {
    const float* frame   = (const float*)d_in[0];
    const unsigned char* done = (const unsigned char*)d_in[1];
    const int*   lact    = (const int*)d_in[2];
    const float* reward  = (const float*)d_in[3];
    const float* core_h0 = (const float*)d_in[4];
    const float* core_c0 = (const float*)d_in[5];
    const float* conv_h0 = (const float*)d_in[6];
    const float* conv_c0 = (const float*)d_in[7];
    const float* cnn_w1  = (const float*)d_in[8];
    const float* cnn_b1  = (const float*)d_in[9];
    const float* cnn_w2  = (const float*)d_in[10];
    const float* cnn_b2  = (const float*)d_in[11];
    const float* lstm_w  = (const float*)d_in[12];
    const float* lstm_b  = (const float*)d_in[13];
    const float* qw1 = (const float*)d_in[14]; const float* qb1 = (const float*)d_in[15];
    const float* qw2 = (const float*)d_in[16]; const float* qb2 = (const float*)d_in[17];
    const float* qw3 = (const float*)d_in[18]; const float* qb3 = (const float*)d_in[19];
    const float* aw1 = (const float*)d_in[20]; const float* ab1 = (const float*)d_in[21];
    const float* aw2 = (const float*)d_in[22]; const float* ab2 = (const float*)d_in[23];
    const float* w_ih = (const float*)d_in[24]; const float* w_hh = (const float*)d_in[25];
    const float* b_ih = (const float*)d_in[26]; const float* b_hh = (const float*)d_in[27];
    const float* pw = (const float*)d_in[28]; const float* pb = (const float*)d_in[29];
    const float* vw = (const float*)d_in[30]; const float* vb = (const float*)d_in[31];

    float* ws = (float*)d_ws;
    float* dout = (float*)d_out;

    // ws layout (float offsets). c1pad [10,485,760 .. 29,753,344) is transient:
    // consumed by c2mfma, then hreA/apack/wihT/whhT are written into that range
    // (strictly after c2mfma in stream order).
    unsigned short* xpad   = (unsigned short*)ws;                         // 20,971,520 u16
    unsigned short* c1pad  = (unsigned short*)(ws + 10485760);            // 38,535,168 u16 (transient)
    unsigned short* hreA   = (unsigned short*)(ws + 10485760);            // 35,389,440 u16
    unsigned short* apack  = (unsigned short*)(ws + 28180480);            // 1,572,864 u16
    float* wihT  = ws + 28966912;      // 262,144
    float* whhT  = ws + 29229056;      // 262,144  (ends 29,491,200 < 29,753,344)
    unsigned short* hpad   = (unsigned short*)(ws + 29753344);            // 1,310,720 u16
    unsigned short* apack2 = (unsigned short*)(ws + 30408704);            // 32,768 u16
    float* gates = ws + 30425088;      // 4,456,448
    float* vh    = ws + 34881536;      // 1,105,920
    float* vc    = ws + 35987456;      // 1,105,920
    float* S     = ws + 37093376;      // 34,560
    float* outs  = ws + 37127936;      // 131,072
    float* ccb   = ws + 37259008;      // 4,096    (total 37,263,104 floats = 149 MB)

    // zero padded planes (interiors overwritten)
    hipMemsetAsync(xpad,  0, (size_t)20971520*2, stream);
    hipMemsetAsync(c1pad, 0, (size_t)38535168*2, stream);

    // CNN
    apack2k<<<128, 256, 0, stream>>>(cnn_w2, apack2);
    conv1k<<<512*52, 256, 0, stream>>>(frame, cnn_w1, cnn_b1, c1pad);
    c2mfma<<<2560, 256, 0, stream>>>(c1pad, apack2, cnn_b2, xpad);

    // c1pad is dead from here on — its range is reused below
    hipMemsetAsync(hpad, 0, (size_t)1310720*2, stream);
    sbasisk<<<135, 256, 0, stream>>>(S);
    apackk<<<6144, 256, 0, stream>>>(lstm_w, apack);
    transk<<<1024, 256, 0, stream>>>(w_ih, wihT, 1024, 256);
    transk<<<1024, 256, 0, stream>>>(w_hh, whhT, 1024, 256);
    h0packk<<<4320, 256, 0, stream>>>(conv_h0, hpad);
    hipMemcpyAsync(vh,  conv_h0, (size_t)16*128*540*sizeof(float), hipMemcpyDeviceToDevice, stream);
    hipMemcpyAsync(vc,  conv_c0, (size_t)16*128*540*sizeof(float), hipMemcpyDeviceToDevice, stream);

    // phase A: vis ConvLSTM over all t
    for (int t = 0; t < T_; ++t){
        gmfma<<<288, 256, 0, stream>>>(xpad, hpad, apack, done, gates, t);
        vupdk<<<4320, 256, 0, stream>>>(gates, lstm_b, done, vh, vc, hpad, hreA, t);
    }

    // phase B: entire core recurrence in one dispatch
    corek2<<<16, 512, 0, stream>>>(hreA, S, qw1,qb1,qw2,qb2,qw3,qb3,
                                   aw1,ab1,aw2,ab2, wihT,whhT,b_ih,b_hh,
                                   reward, lact, done, core_h0, core_c0, ccb, outs);

    finalk<<<512, 64, 0, stream>>>(outs, pw, pb, vw, vb, dout);

    hipMemcpyAsync(dout + 10240,   outs + (size_t)31*B_*256, (size_t)16*256*sizeof(float), hipMemcpyDeviceToDevice, stream);
    hipMemcpyAsync(dout + 14336,   ccb, (size_t)16*256*sizeof(float), hipMemcpyDeviceToDevice, stream);
    hipMemcpyAsync(dout + 18432,   vh,  (size_t)16*128*540*sizeof(float), hipMemcpyDeviceToDevice, stream);
    hipMemcpyAsync(dout + 1124352, vc,  (size_t)16*128*540*sizeof(float), hipMemcpyDeviceToDevice, stream);
}